// Round 3
// baseline (442.507 us; speedup 1.0000x reference)
//
#include <hip/hip_runtime.h>
#include <hip/hip_fp16.h>

#define N_NODES 100000
#define N_EDGES 1600000
#define CH 128
#define OCH 64
#define NBUCKET 391   // ceil(100000/256) dst-buckets of 256 nodes
#define CAP 8192      // bucket capacity (mean 4092, sd ~64)
#define BIN_CHUNK 4096
#define NBLK_AGG 25000  // N_NODES/4 blocks per channel-half pass

typedef _Float16 half8 __attribute__((ext_vector_type(8)));
typedef float f32x4 __attribute__((ext_vector_type(4)));
typedef uint uint2v __attribute__((ext_vector_type(2)));

__device__ __forceinline__ ushort f2h(float f) {
    _Float16 h = (_Float16)f;
    return *(ushort*)&h;
}

__device__ __forceinline__ uint pkadd(uint a, uint b) {
    __half2 r = __hadd2(*(__half2*)&a, *(__half2*)&b);
    return *(uint*)&r;
}

// XOR-swizzled f16 offset inside a [rows][128] f16 tile (r6-proven, 0 conflicts).
__device__ __forceinline__ int swz(int row, int k) {
    return row * 128 + ((((k >> 3) ^ (row & 15)) << 3) | (k & 7));
}

// ---------------- CSR build: LDS-staged counting sort (r6-proven shape) ----------------

__global__ __launch_bounds__(512) void k_bin(const int* __restrict__ src,
                                             const int* __restrict__ dst,
                                             int* __restrict__ bfill,
                                             int* __restrict__ bin) {
    __shared__ int hist[512];
    __shared__ int wbase[512];
    __shared__ int cur[512];
    const int t = threadIdx.x;
    const int e0 = blockIdx.x * BIN_CHUNK;

    hist[t] = 0;
    __syncthreads();

    int ss[8], bb[8], dl[8];
#pragma unroll
    for (int j = 0; j < 8; ++j) {
        int e = e0 + j * 512 + t;
        bb[j] = -1;
        if (e < N_EDGES) {
            int s = src[e], d = dst[e];
            ss[j] = s; dl[j] = d & 255; bb[j] = d >> 8;
            atomicAdd(&hist[bb[j]], 1);
        }
    }
    __syncthreads();

    int v = hist[t];
    for (int off = 1; off < 512; off <<= 1) {
        int tv = (t >= off) ? hist[t - off] : 0;
        __syncthreads();
        hist[t] += tv;
        __syncthreads();
    }
    int excl = hist[t] - v;
    if (t < NBUCKET && v > 0) {
        int gb = atomicAdd(&bfill[t], v);
        wbase[t] = gb - excl;
    }
    cur[t] = excl;
    __syncthreads();

#pragma unroll
    for (int j = 0; j < 8; ++j) {
        if (bb[j] >= 0) {
            int p = atomicAdd(&cur[bb[j]], 1);
            bin[bb[j] * CAP + wbase[bb[j]] + p] = (ss[j] << 8) | dl[j];
        }
    }
}

// block 0: exclusive scan of bucket fills. blocks 1..80: weight prep (fused launch).
__global__ __launch_bounds__(512) void k_scan_prep(const int* __restrict__ bfill,
                                                   int* __restrict__ bbase,
                                                   const float* __restrict__ W1,
                                                   const float* __restrict__ W2,
                                                   const float* __restrict__ Wo,
                                                   ushort* __restrict__ W1s,
                                                   ushort* __restrict__ W2s,
                                                   ushort* __restrict__ WoTs) {
    if (blockIdx.x == 0) {
        __shared__ int tmp[512];
        int t = threadIdx.x;
        int v = (t < NBUCKET) ? bfill[t] : 0;
        tmp[t] = v;
        __syncthreads();
        for (int off = 1; off < 512; off <<= 1) {
            int tv = (t >= off) ? tmp[t - off] : 0;
            __syncthreads();
            tmp[t] += tv;
            __syncthreads();
        }
        if (t < NBUCKET) bbase[t] = tmp[t] - v;
    } else {
        int i = (blockIdx.x - 1) * 512 + threadIdx.x;  // 0..40959
        if (i < 16384) {
            int k = i >> 7, n = i & 127;
            W1s[swz(n, k)] = f2h(W1[i]);
        } else if (i < 32768) {
            int j = i - 16384, k = j >> 7, n = j & 127;
            W2s[swz(n, k)] = f2h(W2[j]);
        } else if (i < 40960) {
            int j = i - 32768, k = j >> 6, n = j & 63;
            WoTs[swz(n, k)] = f2h(Wo[j]);
        }
    }
}

__global__ __launch_bounds__(256) void k_build(const int* __restrict__ bfill,
                                               const int* __restrict__ bbase,
                                               const int* __restrict__ bin,
                                               int* __restrict__ esrc,
                                               int* __restrict__ start,
                                               int* __restrict__ cnt,
                                               float* __restrict__ dis) {
    __shared__ int cnt_l[256];
    __shared__ int cur_l[256];
    __shared__ int sortbuf[CAP];
    const int t = threadIdx.x;
    const int b = blockIdx.x;
    const int n = bfill[b];
    const int base = bbase[b];
    const int* brec = bin + b * CAP;

    cnt_l[t] = 0;
    __syncthreads();
    for (int i = t; i < n; i += 256)
        atomicAdd(&cnt_l[brec[i] & 255], 1);
    __syncthreads();

    int v = cnt_l[t];
    for (int off = 1; off < 256; off <<= 1) {
        int tv = (t >= off) ? cnt_l[t - off] : 0;
        __syncthreads();
        cnt_l[t] += tv;
        __syncthreads();
    }
    int excl = cnt_l[t] - v;
    int node = b * 256 + t;
    if (node < N_NODES) {
        start[node] = base + excl;
        cnt[node] = v;
        dis[node] = rsqrtf((float)(v + 1));  // +1 self-loop
    }
    cur_l[t] = excl;
    __syncthreads();

    for (int i = t; i < n; i += 256) {
        int rec = brec[i];
        int p = atomicAdd(&cur_l[rec & 255], 1);
        sortbuf[p] = rec >> 8;
    }
    __syncthreads();
    for (int i = t; i < n; i += 256)
        esrc[base + i] = sortbuf[i];
}

// ---------------- MFMA GEMM: h[half][r][64] = dis[r] * (A[r] @ W) ----------------
// NOTE: output is written in channel-half-split layout [2][N][64] so that the
// aggregation passes each touch a CONTIGUOUS 12.8 MB hot region (one line/edge).

template <typename IT>
__global__ __launch_bounds__(256) void k_gemm_mfma(const IT* __restrict__ A,
                                                   const ushort* __restrict__ Ws,
                                                   const float* __restrict__ dis,
                                                   ushort* __restrict__ out) {
    __shared__ ushort sB[128 * 128];
    __shared__ ushort sA[64 * 128];
    const int tid = threadIdx.x;
    const int row0 = blockIdx.x * 64;

    for (int i = tid; i < 2048; i += 256)
        ((float4*)sB)[i] = ((const float4*)Ws)[i];

    for (int i = tid; i < 2048; i += 256) {
        int m = i >> 5, u = i & 31, k4 = u << 2;
        int r = row0 + m;
        ushort4 pk = make_ushort4(0, 0, 0, 0);
        if (r < N_NODES) {
            if constexpr (sizeof(IT) == 4) {
                float4 a = ((const float4*)A)[r * 32 + u];
                pk = make_ushort4(f2h(a.x), f2h(a.y), f2h(a.z), f2h(a.w));
            } else {
                pk = ((const ushort4*)A)[r * 32 + u];
            }
        }
        *(ushort4*)&sA[swz(m, k4)] = pk;
    }
    __syncthreads();

    const int lane = tid & 63, wv = tid >> 6;
    const int mrow = lane & 15, quad = lane >> 4;
    f32x4 acc[8] = {};
#pragma unroll
    for (int kc = 0; kc < 4; ++kc) {
        int g = kc * 4 + quad;
        half8 a = *(const half8*)&sA[(wv * 16 + mrow) * 128 + ((g ^ mrow) << 3)];
#pragma unroll
        for (int nt = 0; nt < 8; ++nt) {
            half8 b = *(const half8*)&sB[(nt * 16 + mrow) * 128 + ((g ^ mrow) << 3)];
            acc[nt] = __builtin_amdgcn_mfma_f32_16x16x32_f16(a, b, acc[nt], 0, 0, 0);
        }
    }

    const int rbase = row0 + wv * 16 + quad * 4;
    float ds[4];
#pragma unroll
    for (int rg = 0; rg < 4; ++rg)
        ds[rg] = (rbase + rg < N_NODES) ? dis[rbase + rg] : 0.f;
#pragma unroll
    for (int nt = 0; nt < 8; ++nt) {
        const size_t hbase = (size_t)(nt >> 2) * (N_NODES * 64);
        const int c = (nt & 3) * 16 + mrow;
#pragma unroll
        for (int rg = 0; rg < 4; ++rg) {
            int r = rbase + rg;
            if (r < N_NODES) out[hbase + (size_t)r * 64 + c] = f2h(acc[nt][rg] * ds[rg]);
        }
    }
}

// ---------------- CSR aggregation: two channel-half passes over [2][N][64] h ----------------
// Pass p (blocks [p*25000, (p+1)*25000)): out[v][64p..64p+63] =
//   relu(dis[v]*(sum_e h[p][src_e] + h[p][v]) + bias_half), fp16 pk accumulate.
// One wave per node per pass; 16 lanes x 8B per edge row-half (one 128B line/edge);
// 4 edges/quarter in flight. Hot set per pass = contiguous 12.8 MB.
// esrc loads and out stores are non-temporal to keep L2 for h.

__global__ __launch_bounds__(256) void k_agg(const int* __restrict__ start,
                                             const int* __restrict__ cnt,
                                             const int* __restrict__ esrc,
                                             const ushort* __restrict__ h,
                                             const float* __restrict__ dis,
                                             const float* __restrict__ bias,
                                             ushort* __restrict__ out) {
    const int half = blockIdx.x / NBLK_AGG;
    const int v = (blockIdx.x - half * NBLK_AGG) * 4 + (threadIdx.x >> 6);
    const int lane = threadIdx.x & 63, q = lane >> 4, l = lane & 15;
    const uint2v* h8 = (const uint2v*)(h + (size_t)half * (N_NODES * 64));

    int n = cnt[v];
    const int* ep = esrc + start[v];

    uint aAx = 0, aAy = 0, aBx = 0, aBy = 0;
    int i = q;
    for (; i + 12 < n; i += 16) {  // this quarter: edges i, i+4, i+8, i+12
        int s0 = __builtin_nontemporal_load(ep + i);
        int s1 = __builtin_nontemporal_load(ep + i + 4);
        int s2 = __builtin_nontemporal_load(ep + i + 8);
        int s3 = __builtin_nontemporal_load(ep + i + 12);
        uint2v t0 = h8[s0 * 16 + l];
        uint2v t1 = h8[s1 * 16 + l];
        uint2v t2 = h8[s2 * 16 + l];
        uint2v t3 = h8[s3 * 16 + l];
        aAx = pkadd(aAx, t0.x); aAy = pkadd(aAy, t0.y);
        aBx = pkadd(aBx, t1.x); aBy = pkadd(aBy, t1.y);
        aAx = pkadd(aAx, t2.x); aAy = pkadd(aAy, t2.y);
        aBx = pkadd(aBx, t3.x); aBy = pkadd(aBy, t3.y);
    }
    for (; i < n; i += 4) {
        int s0 = __builtin_nontemporal_load(ep + i);
        uint2v t0 = h8[s0 * 16 + l];
        aAx = pkadd(aAx, t0.x); aAy = pkadd(aAy, t0.y);
    }
    aAx = pkadd(aAx, aBx); aAy = pkadd(aAy, aBy);
    // reduce across the 4 quarters
    aAx = pkadd(aAx, (uint)__shfl_xor((int)aAx, 16));
    aAy = pkadd(aAy, (uint)__shfl_xor((int)aAy, 16));
    aAx = pkadd(aAx, (uint)__shfl_xor((int)aAx, 32));
    aAy = pkadd(aAy, (uint)__shfl_xor((int)aAy, 32));

    if (q == 0) {
        uint2v hvv = h8[v * 16 + l];  // self-loop term h'[v] (this half)
        uint hvx = hvv.x, hvy = hvv.y;
        aAx = pkadd(aAx, hvx); aAy = pkadd(aAy, hvy);
        float s = dis[v];
        float2 a0 = __half22float2(*(__half2*)&aAx);
        float2 a1 = __half22float2(*(__half2*)&aAy);
        float4 b0 = ((const float4*)bias)[half * 16 + l];
        a0.x = fmaxf(a0.x * s + b0.x, 0.f); a0.y = fmaxf(a0.y * s + b0.y, 0.f);
        a1.x = fmaxf(a1.x * s + b0.z, 0.f); a1.y = fmaxf(a1.y * s + b0.w, 0.f);
        __half2 o0 = __float22half2_rn(a0);
        __half2 o1 = __float22half2_rn(a1);
        uint2v ov;
        ov.x = *(uint*)&o0; ov.y = *(uint*)&o1;
        __builtin_nontemporal_store(ov, (uint2v*)out + v * 32 + half * 16 + l);
    }
}

// ---------------- final MFMA: out_f32[N][64] = (x1+x2)@Wo + bo (r6-proven) ----------------

__global__ __launch_bounds__(256) void k_final_mfma(const ushort* __restrict__ x1,
                                                    const ushort* __restrict__ x2,
                                                    const ushort* __restrict__ Ws,
                                                    const float* __restrict__ bo,
                                                    float* __restrict__ out) {
    __shared__ ushort sB[64 * 128];
    __shared__ ushort sA[64 * 128];
    const int tid = threadIdx.x;
    const int row0 = blockIdx.x * 64;

    for (int i = tid; i < 1024; i += 256)
        ((float4*)sB)[i] = ((const float4*)Ws)[i];

    for (int i = tid; i < 2048; i += 256) {
        int m = i >> 5, u = i & 31, k4 = u << 2;
        int r = row0 + m;
        uint2 pk = make_uint2(0, 0);
        if (r < N_NODES) {
            uint2 ua = ((const uint2*)x1)[r * 32 + u];
            uint2 ub = ((const uint2*)x2)[r * 32 + u];
            __half2 s0 = __hadd2(*(__half2*)&ua.x, *(__half2*)&ub.x);
            __half2 s1 = __hadd2(*(__half2*)&ua.y, *(__half2*)&ub.y);
            pk = make_uint2(*(uint*)&s0, *(uint*)&s1);
        }
        *(uint2*)&sA[swz(m, k4)] = pk;
    }
    __syncthreads();

    const int lane = tid & 63, wv = tid >> 6;
    const int mrow = lane & 15, quad = lane >> 4;
    f32x4 acc[4] = {};
#pragma unroll
    for (int kc = 0; kc < 4; ++kc) {
        int g = kc * 4 + quad;
        half8 a = *(const half8*)&sA[(wv * 16 + mrow) * 128 + ((g ^ mrow) << 3)];
#pragma unroll
        for (int nt = 0; nt < 4; ++nt) {
            half8 b = *(const half8*)&sB[(nt * 16 + mrow) * 128 + ((g ^ mrow) << 3)];
            acc[nt] = __builtin_amdgcn_mfma_f32_16x16x32_f16(a, b, acc[nt], 0, 0, 0);
        }
    }

    const int rbase = row0 + wv * 16 + quad * 4;
#pragma unroll
    for (int nt = 0; nt < 4; ++nt) {
        float bb = bo[nt * 16 + mrow];
#pragma unroll
        for (int rg = 0; rg < 4; ++rg) {
            int r = rbase + rg;
            if (r < N_NODES) out[(size_t)r * 64 + nt * 16 + mrow] = acc[nt][rg] + bb;
        }
    }
}

// ---------------- launch ----------------

extern "C" void kernel_launch(void* const* d_in, const int* in_sizes, int n_in,
                              void* d_out, int out_size, void* d_ws, size_t ws_size,
                              hipStream_t stream) {
    const float* x  = (const float*)d_in[0];
    const int*   ei = (const int*)d_in[1];
    const int*   src = ei;
    const int*   dst = ei + N_EDGES;
    const float* W1 = (const float*)d_in[2];
    const float* b1 = (const float*)d_in[3];
    const float* W2 = (const float*)d_in[4];
    const float* b2 = (const float*)d_in[5];
    const float* Wo = (const float*)d_in[6];
    const float* bo = (const float*)d_in[7];
    float* out = (float*)d_out;

    char* ws = (char*)d_ws;
    int*    bfill  = (int*)ws;            ws += 2048;
    int*    bbase  = (int*)ws;            ws += 2048;
    int*    cnt    = (int*)ws;            ws += 400000;
    int*    start  = (int*)ws;            ws += 400000;
    float*  dis    = (float*)ws;          ws += 400000;
    int*    bin    = (int*)ws;            ws += (size_t)NBUCKET * CAP * 4;  // 12.8 MB
    int*    esrc   = (int*)ws;            ws += (size_t)N_EDGES * 4;
    ushort* W1s    = (ushort*)ws;         ws += 32768;
    ushort* W2s    = (ushort*)ws;         ws += 32768;
    ushort* WoTs   = (ushort*)ws;         ws += 16384;
    ushort* h      = (ushort*)ws;         ws += (size_t)N_NODES * CH * 2;  // [2][N][64]
    ushort* x1     = (ushort*)ws;         ws += (size_t)N_NODES * CH * 2;
    ushort* x2     = (ushort*)ws;

    const int B = 256;
    const int gG = (N_NODES + 63) / 64;   // 1563

    // CSR build (LDS-staged counting sort) + weight prep
    hipMemsetAsync(bfill, 0, 2048, stream);
    k_bin<<<(N_EDGES + BIN_CHUNK - 1) / BIN_CHUNK, 512, 0, stream>>>(src, dst, bfill, bin);
    k_scan_prep<<<81, 512, 0, stream>>>(bfill, bbase, W1, W2, Wo, W1s, W2s, WoTs);
    k_build<<<NBUCKET, 256, 0, stream>>>(bfill, bbase, bin, esrc, start, cnt, dis);

    // layer 1
    k_gemm_mfma<float><<<gG, B, 0, stream>>>(x, W1s, dis, h);
    k_agg<<<2 * NBLK_AGG, B, 0, stream>>>(start, cnt, esrc, h, dis, b1, x1);

    // layer 2
    k_gemm_mfma<ushort><<<gG, B, 0, stream>>>(x1, W2s, dis, h);
    k_agg<<<2 * NBLK_AGG, B, 0, stream>>>(start, cnt, esrc, h, dis, b2, x2);

    // output projection
    k_final_mfma<<<gG, B, 0, stream>>>(x1, x2, WoTs, bo, out);
}

// Round 4
// 383.990 us; speedup vs baseline: 1.1524x; 1.1524x over previous
//
#include <hip/hip_runtime.h>
#include <hip/hip_fp16.h>

#define N_NODES 100000
#define N_EDGES 1600000
#define CH 128
#define OCH 64
#define NBUCKET 391   // ceil(100000/256) dst-buckets of 256 nodes
#define CAP 8192      // bucket capacity (mean 4092, sd ~64)
#define BIN_CHUNK 4096

typedef _Float16 half8 __attribute__((ext_vector_type(8)));
typedef float f32x4 __attribute__((ext_vector_type(4)));

__device__ __forceinline__ ushort f2h(float f) {
    _Float16 h = (_Float16)f;
    return *(ushort*)&h;
}

__device__ __forceinline__ uint pkadd(uint a, uint b) {
    __half2 r = __hadd2(*(__half2*)&a, *(__half2*)&b);
    return *(uint*)&r;
}

__device__ __forceinline__ uint4 pk4(uint4 a, uint4 b) {
    a.x = pkadd(a.x, b.x); a.y = pkadd(a.y, b.y);
    a.z = pkadd(a.z, b.z); a.w = pkadd(a.w, b.w);
    return a;
}

// XOR-swizzled f16 offset inside a [rows][128] f16 tile (r6-proven, 0 conflicts).
__device__ __forceinline__ int swz(int row, int k) {
    return row * 128 + ((((k >> 3) ^ (row & 15)) << 3) | (k & 7));
}

// ---------------- CSR build: LDS-staged counting sort (r6-proven shape) ----------------

__global__ __launch_bounds__(512) void k_bin(const int* __restrict__ src,
                                             const int* __restrict__ dst,
                                             int* __restrict__ bfill,
                                             int* __restrict__ bin) {
    __shared__ int hist[512];
    __shared__ int wbase[512];
    __shared__ int cur[512];
    const int t = threadIdx.x;
    const int e0 = blockIdx.x * BIN_CHUNK;

    hist[t] = 0;
    __syncthreads();

    int ss[8], bb[8], dl[8];
#pragma unroll
    for (int j = 0; j < 8; ++j) {
        int e = e0 + j * 512 + t;
        bb[j] = -1;
        if (e < N_EDGES) {
            int s = src[e], d = dst[e];
            ss[j] = s; dl[j] = d & 255; bb[j] = d >> 8;
            atomicAdd(&hist[bb[j]], 1);
        }
    }
    __syncthreads();

    int v = hist[t];
    for (int off = 1; off < 512; off <<= 1) {
        int tv = (t >= off) ? hist[t - off] : 0;
        __syncthreads();
        hist[t] += tv;
        __syncthreads();
    }
    int excl = hist[t] - v;
    if (t < NBUCKET && v > 0) {
        int gb = atomicAdd(&bfill[t], v);
        wbase[t] = gb - excl;
    }
    cur[t] = excl;
    __syncthreads();

#pragma unroll
    for (int j = 0; j < 8; ++j) {
        if (bb[j] >= 0) {
            int p = atomicAdd(&cur[bb[j]], 1);
            bin[bb[j] * CAP + wbase[bb[j]] + p] = (ss[j] << 8) | dl[j];
        }
    }
}

// block 0: exclusive scan of bucket fills. blocks 1..80: weight prep (fused launch).
__global__ __launch_bounds__(512) void k_scan_prep(const int* __restrict__ bfill,
                                                   int* __restrict__ bbase,
                                                   const float* __restrict__ W1,
                                                   const float* __restrict__ W2,
                                                   const float* __restrict__ Wo,
                                                   ushort* __restrict__ W1s,
                                                   ushort* __restrict__ W2s,
                                                   ushort* __restrict__ WoTs) {
    if (blockIdx.x == 0) {
        __shared__ int tmp[512];
        int t = threadIdx.x;
        int v = (t < NBUCKET) ? bfill[t] : 0;
        tmp[t] = v;
        __syncthreads();
        for (int off = 1; off < 512; off <<= 1) {
            int tv = (t >= off) ? tmp[t - off] : 0;
            __syncthreads();
            tmp[t] += tv;
            __syncthreads();
        }
        if (t < NBUCKET) bbase[t] = tmp[t] - v;
    } else {
        int i = (blockIdx.x - 1) * 512 + threadIdx.x;  // 0..40959
        if (i < 16384) {
            int k = i >> 7, n = i & 127;
            W1s[swz(n, k)] = f2h(W1[i]);
        } else if (i < 32768) {
            int j = i - 16384, k = j >> 7, n = j & 127;
            W2s[swz(n, k)] = f2h(W2[j]);
        } else if (i < 40960) {
            int j = i - 32768, k = j >> 6, n = j & 63;
            WoTs[swz(n, k)] = f2h(Wo[j]);
        }
    }
}

__global__ __launch_bounds__(256) void k_build(const int* __restrict__ bfill,
                                               const int* __restrict__ bbase,
                                               const int* __restrict__ bin,
                                               int* __restrict__ esrc,
                                               int* __restrict__ start,
                                               int* __restrict__ cnt,
                                               float* __restrict__ dis) {
    __shared__ int cnt_l[256];
    __shared__ int cur_l[256];
    __shared__ int sortbuf[CAP];
    const int t = threadIdx.x;
    const int b = blockIdx.x;
    const int n = bfill[b];
    const int base = bbase[b];
    const int* brec = bin + b * CAP;

    cnt_l[t] = 0;
    __syncthreads();
    for (int i = t; i < n; i += 256)
        atomicAdd(&cnt_l[brec[i] & 255], 1);
    __syncthreads();

    int v = cnt_l[t];
    for (int off = 1; off < 256; off <<= 1) {
        int tv = (t >= off) ? cnt_l[t - off] : 0;
        __syncthreads();
        cnt_l[t] += tv;
        __syncthreads();
    }
    int excl = cnt_l[t] - v;
    int node = b * 256 + t;
    if (node < N_NODES) {
        start[node] = base + excl;
        cnt[node] = v;
        dis[node] = rsqrtf((float)(v + 1));  // +1 self-loop
    }
    cur_l[t] = excl;
    __syncthreads();

    for (int i = t; i < n; i += 256) {
        int rec = brec[i];
        int p = atomicAdd(&cur_l[rec & 255], 1);
        sortbuf[p] = rec >> 8;
    }
    __syncthreads();
    for (int i = t; i < n; i += 256)
        esrc[base + i] = sortbuf[i];
}

// ---------------- MFMA GEMM: out_f16[r] = dis[r] * (A[r] @ W) (r6-proven) ----------------

template <typename IT>
__global__ __launch_bounds__(256) void k_gemm_mfma(const IT* __restrict__ A,
                                                   const ushort* __restrict__ Ws,
                                                   const float* __restrict__ dis,
                                                   ushort* __restrict__ out) {
    __shared__ ushort sB[128 * 128];
    __shared__ ushort sA[64 * 128];
    const int tid = threadIdx.x;
    const int row0 = blockIdx.x * 64;

    for (int i = tid; i < 2048; i += 256)
        ((float4*)sB)[i] = ((const float4*)Ws)[i];

    for (int i = tid; i < 2048; i += 256) {
        int m = i >> 5, u = i & 31, k4 = u << 2;
        int r = row0 + m;
        ushort4 pk = make_ushort4(0, 0, 0, 0);
        if (r < N_NODES) {
            if constexpr (sizeof(IT) == 4) {
                float4 a = ((const float4*)A)[r * 32 + u];
                pk = make_ushort4(f2h(a.x), f2h(a.y), f2h(a.z), f2h(a.w));
            } else {
                pk = ((const ushort4*)A)[r * 32 + u];
            }
        }
        *(ushort4*)&sA[swz(m, k4)] = pk;
    }
    __syncthreads();

    const int lane = tid & 63, wv = tid >> 6;
    const int mrow = lane & 15, quad = lane >> 4;
    f32x4 acc[8] = {};
#pragma unroll
    for (int kc = 0; kc < 4; ++kc) {
        int g = kc * 4 + quad;
        half8 a = *(const half8*)&sA[(wv * 16 + mrow) * 128 + ((g ^ mrow) << 3)];
#pragma unroll
        for (int nt = 0; nt < 8; ++nt) {
            half8 b = *(const half8*)&sB[(nt * 16 + mrow) * 128 + ((g ^ mrow) << 3)];
            acc[nt] = __builtin_amdgcn_mfma_f32_16x16x32_f16(a, b, acc[nt], 0, 0, 0);
        }
    }

    const int rbase = row0 + wv * 16 + quad * 4;
    float ds[4];
#pragma unroll
    for (int rg = 0; rg < 4; ++rg)
        ds[rg] = (rbase + rg < N_NODES) ? dis[rbase + rg] : 0.f;
#pragma unroll
    for (int nt = 0; nt < 8; ++nt) {
#pragma unroll
        for (int rg = 0; rg < 4; ++rg) {
            int r = rbase + rg;
            if (r < N_NODES) out[r * 128 + nt * 16 + mrow] = f2h(acc[nt][rg] * ds[rg]);
        }
    }
}

// ---------------- CSR aggregation: 3 nodes per wave, 12 gather-instrs in flight ----------------
// k_agg is latency/concurrency-bound (r3 A/B: halving bytes-in-flight doubled time).
// Each wave owns 3 nodes; the lockstep main loop issues 12 independent uint4 gathers
// (12 KB in flight) before any accumulate. Per-node edge order, aA/aB alternation and
// quarter-shuffle combine are IDENTICAL to the r0 kernel -> bit-identical output.

__device__ __forceinline__ void agg_finish(uint4 a, int v, int l, int q,
                                           const uint4* __restrict__ h16,
                                           const float* __restrict__ dis,
                                           const float* __restrict__ bias,
                                           ushort* __restrict__ out) {
    // reduce across the 4 quarters
    a.x = pkadd(a.x, (uint)__shfl_xor((int)a.x, 16));
    a.y = pkadd(a.y, (uint)__shfl_xor((int)a.y, 16));
    a.z = pkadd(a.z, (uint)__shfl_xor((int)a.z, 16));
    a.w = pkadd(a.w, (uint)__shfl_xor((int)a.w, 16));
    a.x = pkadd(a.x, (uint)__shfl_xor((int)a.x, 32));
    a.y = pkadd(a.y, (uint)__shfl_xor((int)a.y, 32));
    a.z = pkadd(a.z, (uint)__shfl_xor((int)a.z, 32));
    a.w = pkadd(a.w, (uint)__shfl_xor((int)a.w, 32));

    if (q == 0 && v < N_NODES) {
        uint4 hv = h16[v * 16 + l];  // self-loop term h'[v]
        a.x = pkadd(a.x, hv.x); a.y = pkadd(a.y, hv.y);
        a.z = pkadd(a.z, hv.z); a.w = pkadd(a.w, hv.w);
        float s = dis[v];
        float2 a0 = __half22float2(*(__half2*)&a.x);
        float2 a1 = __half22float2(*(__half2*)&a.y);
        float2 a2 = __half22float2(*(__half2*)&a.z);
        float2 a3 = __half22float2(*(__half2*)&a.w);
        float4 b0 = ((const float4*)bias)[2 * l];
        float4 b1 = ((const float4*)bias)[2 * l + 1];
        a0.x = fmaxf(a0.x * s + b0.x, 0.f); a0.y = fmaxf(a0.y * s + b0.y, 0.f);
        a1.x = fmaxf(a1.x * s + b0.z, 0.f); a1.y = fmaxf(a1.y * s + b0.w, 0.f);
        a2.x = fmaxf(a2.x * s + b1.x, 0.f); a2.y = fmaxf(a2.y * s + b1.y, 0.f);
        a3.x = fmaxf(a3.x * s + b1.z, 0.f); a3.y = fmaxf(a3.y * s + b1.w, 0.f);
        __half2 o0 = __float22half2_rn(a0);
        __half2 o1 = __float22half2_rn(a1);
        __half2 o2 = __float22half2_rn(a2);
        __half2 o3 = __float22half2_rn(a3);
        ((uint4*)out)[v * 16 + l] =
            make_uint4(*(uint*)&o0, *(uint*)&o1, *(uint*)&o2, *(uint*)&o3);
    }
}

__global__ __launch_bounds__(256) void k_agg(const int* __restrict__ start,
                                             const int* __restrict__ cnt,
                                             const int* __restrict__ esrc,
                                             const ushort* __restrict__ h,
                                             const float* __restrict__ dis,
                                             const float* __restrict__ bias,
                                             ushort* __restrict__ out) {
    const int w = threadIdx.x >> 6;
    const int vb = blockIdx.x * 12 + w * 3;   // 3 nodes per wave
    const int lane = threadIdx.x & 63, q = lane >> 4, l = lane & 15;
    const uint4* h16 = (const uint4*)h;

    const int v0 = vb, v1 = vb + 1, v2 = vb + 2;
    const int n0 = (v0 < N_NODES) ? cnt[v0] : 0;
    const int n1 = (v1 < N_NODES) ? cnt[v1] : 0;
    const int n2 = (v2 < N_NODES) ? cnt[v2] : 0;
    const int* ep0 = esrc + ((v0 < N_NODES) ? start[v0] : 0);
    const int* ep1 = esrc + ((v1 < N_NODES) ? start[v1] : 0);
    const int* ep2 = esrc + ((v2 < N_NODES) ? start[v2] : 0);

    uint4 aA0 = make_uint4(0,0,0,0), aB0 = make_uint4(0,0,0,0);
    uint4 aA1 = make_uint4(0,0,0,0), aB1 = make_uint4(0,0,0,0);
    uint4 aA2 = make_uint4(0,0,0,0), aB2 = make_uint4(0,0,0,0);

    int i0 = q, i1 = q, i2 = q;
    // lockstep main loop: 12 independent gathers in flight
    while ((i0 + 12 < n0) & (i1 + 12 < n1) & (i2 + 12 < n2)) {
        int s00 = ep0[i0], s01 = ep0[i0 + 4], s02 = ep0[i0 + 8], s03 = ep0[i0 + 12];
        int s10 = ep1[i1], s11 = ep1[i1 + 4], s12 = ep1[i1 + 8], s13 = ep1[i1 + 12];
        int s20 = ep2[i2], s21 = ep2[i2 + 4], s22 = ep2[i2 + 8], s23 = ep2[i2 + 12];
        uint4 t00 = h16[s00 * 16 + l], t01 = h16[s01 * 16 + l];
        uint4 t02 = h16[s02 * 16 + l], t03 = h16[s03 * 16 + l];
        uint4 t10 = h16[s10 * 16 + l], t11 = h16[s11 * 16 + l];
        uint4 t12 = h16[s12 * 16 + l], t13 = h16[s13 * 16 + l];
        uint4 t20 = h16[s20 * 16 + l], t21 = h16[s21 * 16 + l];
        uint4 t22 = h16[s22 * 16 + l], t23 = h16[s23 * 16 + l];
        aA0 = pk4(aA0, t00); aB0 = pk4(aB0, t01); aA0 = pk4(aA0, t02); aB0 = pk4(aB0, t03);
        aA1 = pk4(aA1, t10); aB1 = pk4(aB1, t11); aA1 = pk4(aA1, t12); aB1 = pk4(aB1, t13);
        aA2 = pk4(aA2, t20); aB2 = pk4(aB2, t21); aA2 = pk4(aA2, t22); aB2 = pk4(aB2, t23);
        i0 += 16; i1 += 16; i2 += 16;
    }
    // per-node drains (same structure as r0 main+tail; order per node unchanged)
    for (; i0 + 12 < n0; i0 += 16) {
        int s0 = ep0[i0], s1 = ep0[i0 + 4], s2 = ep0[i0 + 8], s3 = ep0[i0 + 12];
        uint4 t0 = h16[s0 * 16 + l], t1 = h16[s1 * 16 + l];
        uint4 t2 = h16[s2 * 16 + l], t3 = h16[s3 * 16 + l];
        aA0 = pk4(aA0, t0); aB0 = pk4(aB0, t1); aA0 = pk4(aA0, t2); aB0 = pk4(aB0, t3);
    }
    for (; i0 < n0; i0 += 4) { uint4 t = h16[ep0[i0] * 16 + l]; aA0 = pk4(aA0, t); }
    for (; i1 + 12 < n1; i1 += 16) {
        int s0 = ep1[i1], s1 = ep1[i1 + 4], s2 = ep1[i1 + 8], s3 = ep1[i1 + 12];
        uint4 t0 = h16[s0 * 16 + l], t1 = h16[s1 * 16 + l];
        uint4 t2 = h16[s2 * 16 + l], t3 = h16[s3 * 16 + l];
        aA1 = pk4(aA1, t0); aB1 = pk4(aB1, t1); aA1 = pk4(aA1, t2); aB1 = pk4(aB1, t3);
    }
    for (; i1 < n1; i1 += 4) { uint4 t = h16[ep1[i1] * 16 + l]; aA1 = pk4(aA1, t); }
    for (; i2 + 12 < n2; i2 += 16) {
        int s0 = ep2[i2], s1 = ep2[i2 + 4], s2 = ep2[i2 + 8], s3 = ep2[i2 + 12];
        uint4 t0 = h16[s0 * 16 + l], t1 = h16[s1 * 16 + l];
        uint4 t2 = h16[s2 * 16 + l], t3 = h16[s3 * 16 + l];
        aA2 = pk4(aA2, t0); aB2 = pk4(aB2, t1); aA2 = pk4(aA2, t2); aB2 = pk4(aB2, t3);
    }
    for (; i2 < n2; i2 += 4) { uint4 t = h16[ep2[i2] * 16 + l]; aA2 = pk4(aA2, t); }

    aA0 = pk4(aA0, aB0);
    aA1 = pk4(aA1, aB1);
    aA2 = pk4(aA2, aB2);

    agg_finish(aA0, v0, l, q, h16, dis, bias, out);
    agg_finish(aA1, v1, l, q, h16, dis, bias, out);
    agg_finish(aA2, v2, l, q, h16, dis, bias, out);
}

// ---------------- final MFMA: out_f32[N][64] = (x1+x2)@Wo + bo (r6-proven) ----------------

__global__ __launch_bounds__(256) void k_final_mfma(const ushort* __restrict__ x1,
                                                    const ushort* __restrict__ x2,
                                                    const ushort* __restrict__ Ws,
                                                    const float* __restrict__ bo,
                                                    float* __restrict__ out) {
    __shared__ ushort sB[64 * 128];
    __shared__ ushort sA[64 * 128];
    const int tid = threadIdx.x;
    const int row0 = blockIdx.x * 64;

    for (int i = tid; i < 1024; i += 256)
        ((float4*)sB)[i] = ((const float4*)Ws)[i];

    for (int i = tid; i < 2048; i += 256) {
        int m = i >> 5, u = i & 31, k4 = u << 2;
        int r = row0 + m;
        uint2 pk = make_uint2(0, 0);
        if (r < N_NODES) {
            uint2 ua = ((const uint2*)x1)[r * 32 + u];
            uint2 ub = ((const uint2*)x2)[r * 32 + u];
            __half2 s0 = __hadd2(*(__half2*)&ua.x, *(__half2*)&ub.x);
            __half2 s1 = __hadd2(*(__half2*)&ua.y, *(__half2*)&ub.y);
            pk = make_uint2(*(uint*)&s0, *(uint*)&s1);
        }
        *(uint2*)&sA[swz(m, k4)] = pk;
    }
    __syncthreads();

    const int lane = tid & 63, wv = tid >> 6;
    const int mrow = lane & 15, quad = lane >> 4;
    f32x4 acc[4] = {};
#pragma unroll
    for (int kc = 0; kc < 4; ++kc) {
        int g = kc * 4 + quad;
        half8 a = *(const half8*)&sA[(wv * 16 + mrow) * 128 + ((g ^ mrow) << 3)];
#pragma unroll
        for (int nt = 0; nt < 4; ++nt) {
            half8 b = *(const half8*)&sB[(nt * 16 + mrow) * 128 + ((g ^ mrow) << 3)];
            acc[nt] = __builtin_amdgcn_mfma_f32_16x16x32_f16(a, b, acc[nt], 0, 0, 0);
        }
    }

    const int rbase = row0 + wv * 16 + quad * 4;
#pragma unroll
    for (int nt = 0; nt < 4; ++nt) {
        float bb = bo[nt * 16 + mrow];
#pragma unroll
        for (int rg = 0; rg < 4; ++rg) {
            int r = rbase + rg;
            if (r < N_NODES) out[(size_t)r * 64 + nt * 16 + mrow] = acc[nt][rg] + bb;
        }
    }
}

// ---------------- launch ----------------

extern "C" void kernel_launch(void* const* d_in, const int* in_sizes, int n_in,
                              void* d_out, int out_size, void* d_ws, size_t ws_size,
                              hipStream_t stream) {
    const float* x  = (const float*)d_in[0];
    const int*   ei = (const int*)d_in[1];
    const int*   src = ei;
    const int*   dst = ei + N_EDGES;
    const float* W1 = (const float*)d_in[2];
    const float* b1 = (const float*)d_in[3];
    const float* W2 = (const float*)d_in[4];
    const float* b2 = (const float*)d_in[5];
    const float* Wo = (const float*)d_in[6];
    const float* bo = (const float*)d_in[7];
    float* out = (float*)d_out;

    char* ws = (char*)d_ws;
    int*    bfill  = (int*)ws;            ws += 2048;
    int*    bbase  = (int*)ws;            ws += 2048;
    int*    cnt    = (int*)ws;            ws += 400000;
    int*    start  = (int*)ws;            ws += 400000;
    float*  dis    = (float*)ws;          ws += 400000;
    int*    bin    = (int*)ws;            ws += (size_t)NBUCKET * CAP * 4;  // 12.8 MB
    int*    esrc   = (int*)ws;            ws += (size_t)N_EDGES * 4;
    ushort* W1s    = (ushort*)ws;         ws += 32768;
    ushort* W2s    = (ushort*)ws;         ws += 32768;
    ushort* WoTs   = (ushort*)ws;         ws += 16384;
    ushort* h      = (ushort*)ws;         ws += (size_t)N_NODES * CH * 2;
    ushort* x1     = (ushort*)ws;         ws += (size_t)N_NODES * CH * 2;
    ushort* x2     = (ushort*)ws;

    const int B = 256;
    const int gG = (N_NODES + 63) / 64;       // 1563
    const int gA = (N_NODES + 11) / 12;       // 8334 (12 nodes per block)

    // CSR build (LDS-staged counting sort) + weight prep
    hipMemsetAsync(bfill, 0, 2048, stream);
    k_bin<<<(N_EDGES + BIN_CHUNK - 1) / BIN_CHUNK, 512, 0, stream>>>(src, dst, bfill, bin);
    k_scan_prep<<<81, 512, 0, stream>>>(bfill, bbase, W1, W2, Wo, W1s, W2s, WoTs);
    k_build<<<NBUCKET, 256, 0, stream>>>(bfill, bbase, bin, esrc, start, cnt, dis);

    // layer 1
    k_gemm_mfma<float><<<gG, B, 0, stream>>>(x, W1s, dis, h);
    k_agg<<<gA, B, 0, stream>>>(start, cnt, esrc, h, dis, b1, x1);

    // layer 2
    k_gemm_mfma<ushort><<<gG, B, 0, stream>>>(x1, W2s, dis, h);
    k_agg<<<gA, B, 0, stream>>>(start, cnt, esrc, h, dis, b2, x2);

    // output projection
    k_final_mfma<<<gG, B, 0, stream>>>(x1, x2, WoTs, bo, out);
}

// Round 5
// 336.959 us; speedup vs baseline: 1.3132x; 1.1396x over previous
//
#include <hip/hip_runtime.h>
#include <hip/hip_fp16.h>

#define N_NODES 100000
#define N_EDGES 1600000
#define CH 128
#define OCH 64
#define NBUCKET 391   // ceil(100000/256) dst-buckets of 256 nodes
#define CAP 8192      // bucket capacity (mean 4092, sd ~64)
#define BIN_CHUNK 4096
#define ZROW N_NODES  // index of the guaranteed-zero h row (predication target)

typedef _Float16 half8 __attribute__((ext_vector_type(8)));
typedef float f32x4 __attribute__((ext_vector_type(4)));

__device__ __forceinline__ ushort f2h(float f) {
    _Float16 h = (_Float16)f;
    return *(ushort*)&h;
}

__device__ __forceinline__ uint pkadd(uint a, uint b) {
    __half2 r = __hadd2(*(__half2*)&a, *(__half2*)&b);
    return *(uint*)&r;
}

__device__ __forceinline__ uint4 pk4(uint4 a, uint4 b) {
    a.x = pkadd(a.x, b.x); a.y = pkadd(a.y, b.y);
    a.z = pkadd(a.z, b.z); a.w = pkadd(a.w, b.w);
    return a;
}

// XOR-swizzled f16 offset inside a [rows][128] f16 tile (r6-proven, 0 conflicts).
__device__ __forceinline__ int swz(int row, int k) {
    return row * 128 + ((((k >> 3) ^ (row & 15)) << 3) | (k & 7));
}

// ---------------- CSR build: LDS-staged counting sort (r6-proven shape) ----------------

__global__ __launch_bounds__(512) void k_bin(const int* __restrict__ src,
                                             const int* __restrict__ dst,
                                             int* __restrict__ bfill,
                                             int* __restrict__ bin) {
    __shared__ int hist[512];
    __shared__ int wbase[512];
    __shared__ int cur[512];
    const int t = threadIdx.x;
    const int e0 = blockIdx.x * BIN_CHUNK;

    hist[t] = 0;
    __syncthreads();

    int ss[8], bb[8], dl[8];
#pragma unroll
    for (int j = 0; j < 8; ++j) {
        int e = e0 + j * 512 + t;
        bb[j] = -1;
        if (e < N_EDGES) {
            int s = src[e], d = dst[e];
            ss[j] = s; dl[j] = d & 255; bb[j] = d >> 8;
            atomicAdd(&hist[bb[j]], 1);
        }
    }
    __syncthreads();

    int v = hist[t];
    for (int off = 1; off < 512; off <<= 1) {
        int tv = (t >= off) ? hist[t - off] : 0;
        __syncthreads();
        hist[t] += tv;
        __syncthreads();
    }
    int excl = hist[t] - v;
    if (t < NBUCKET && v > 0) {
        int gb = atomicAdd(&bfill[t], v);
        wbase[t] = gb - excl;
    }
    cur[t] = excl;
    __syncthreads();

#pragma unroll
    for (int j = 0; j < 8; ++j) {
        if (bb[j] >= 0) {
            int p = atomicAdd(&cur[bb[j]], 1);
            bin[bb[j] * CAP + wbase[bb[j]] + p] = (ss[j] << 8) | dl[j];
        }
    }
}

// block 0: exclusive scan of bucket fills. blocks 1..80: weight prep (fused launch).
__global__ __launch_bounds__(512) void k_scan_prep(const int* __restrict__ bfill,
                                                   int* __restrict__ bbase,
                                                   const float* __restrict__ W1,
                                                   const float* __restrict__ W2,
                                                   const float* __restrict__ Wo,
                                                   ushort* __restrict__ W1s,
                                                   ushort* __restrict__ W2s,
                                                   ushort* __restrict__ WoTs) {
    if (blockIdx.x == 0) {
        __shared__ int tmp[512];
        int t = threadIdx.x;
        int v = (t < NBUCKET) ? bfill[t] : 0;
        tmp[t] = v;
        __syncthreads();
        for (int off = 1; off < 512; off <<= 1) {
            int tv = (t >= off) ? tmp[t - off] : 0;
            __syncthreads();
            tmp[t] += tv;
            __syncthreads();
        }
        if (t < NBUCKET) bbase[t] = tmp[t] - v;
    } else {
        int i = (blockIdx.x - 1) * 512 + threadIdx.x;  // 0..40959
        if (i < 16384) {
            int k = i >> 7, n = i & 127;
            W1s[swz(n, k)] = f2h(W1[i]);
        } else if (i < 32768) {
            int j = i - 16384, k = j >> 7, n = j & 127;
            W2s[swz(n, k)] = f2h(W2[j]);
        } else if (i < 40960) {
            int j = i - 32768, k = j >> 6, n = j & 63;
            WoTs[swz(n, k)] = f2h(Wo[j]);
        }
    }
}

__global__ __launch_bounds__(256) void k_build(const int* __restrict__ bfill,
                                               const int* __restrict__ bbase,
                                               const int* __restrict__ bin,
                                               int* __restrict__ esrc,
                                               int2* __restrict__ scnt,
                                               float* __restrict__ dis) {
    __shared__ int cnt_l[256];
    __shared__ int cur_l[256];
    __shared__ int sortbuf[CAP];
    const int t = threadIdx.x;
    const int b = blockIdx.x;
    const int n = bfill[b];
    const int base = bbase[b];
    const int* brec = bin + b * CAP;

    cnt_l[t] = 0;
    __syncthreads();
    for (int i = t; i < n; i += 256)
        atomicAdd(&cnt_l[brec[i] & 255], 1);
    __syncthreads();

    int v = cnt_l[t];
    for (int off = 1; off < 256; off <<= 1) {
        int tv = (t >= off) ? cnt_l[t - off] : 0;
        __syncthreads();
        cnt_l[t] += tv;
        __syncthreads();
    }
    int excl = cnt_l[t] - v;
    int node = b * 256 + t;
    if (node < N_NODES) {
        scnt[node] = make_int2(base + excl, v);
        dis[node] = rsqrtf((float)(v + 1));  // +1 self-loop
    }
    cur_l[t] = excl;
    __syncthreads();

    for (int i = t; i < n; i += 256) {
        int rec = brec[i];
        int p = atomicAdd(&cur_l[rec & 255], 1);
        sortbuf[p] = rec >> 8;
    }
    __syncthreads();
    for (int i = t; i < n; i += 256)
        esrc[base + i] = sortbuf[i];
}

// ---------------- MFMA GEMM: out_f16[r] = dis[r] * (A[r] @ W) (r6-proven) ----------------

template <typename IT>
__global__ __launch_bounds__(256) void k_gemm_mfma(const IT* __restrict__ A,
                                                   const ushort* __restrict__ Ws,
                                                   const float* __restrict__ dis,
                                                   ushort* __restrict__ out) {
    __shared__ ushort sB[128 * 128];
    __shared__ ushort sA[64 * 128];
    const int tid = threadIdx.x;
    const int row0 = blockIdx.x * 64;

    for (int i = tid; i < 2048; i += 256)
        ((float4*)sB)[i] = ((const float4*)Ws)[i];

    for (int i = tid; i < 2048; i += 256) {
        int m = i >> 5, u = i & 31, k4 = u << 2;
        int r = row0 + m;
        ushort4 pk = make_ushort4(0, 0, 0, 0);
        if (r < N_NODES) {
            if constexpr (sizeof(IT) == 4) {
                float4 a = ((const float4*)A)[r * 32 + u];
                pk = make_ushort4(f2h(a.x), f2h(a.y), f2h(a.z), f2h(a.w));
            } else {
                pk = ((const ushort4*)A)[r * 32 + u];
            }
        }
        *(ushort4*)&sA[swz(m, k4)] = pk;
    }
    __syncthreads();

    const int lane = tid & 63, wv = tid >> 6;
    const int mrow = lane & 15, quad = lane >> 4;
    f32x4 acc[8] = {};
#pragma unroll
    for (int kc = 0; kc < 4; ++kc) {
        int g = kc * 4 + quad;
        half8 a = *(const half8*)&sA[(wv * 16 + mrow) * 128 + ((g ^ mrow) << 3)];
#pragma unroll
        for (int nt = 0; nt < 8; ++nt) {
            half8 b = *(const half8*)&sB[(nt * 16 + mrow) * 128 + ((g ^ mrow) << 3)];
            acc[nt] = __builtin_amdgcn_mfma_f32_16x16x32_f16(a, b, acc[nt], 0, 0, 0);
        }
    }

    const int rbase = row0 + wv * 16 + quad * 4;
    float ds[4];
#pragma unroll
    for (int rg = 0; rg < 4; ++rg)
        ds[rg] = (rbase + rg < N_NODES) ? dis[rbase + rg] : 0.f;
#pragma unroll
    for (int nt = 0; nt < 8; ++nt) {
#pragma unroll
        for (int rg = 0; rg < 4; ++rg) {
            int r = rbase + rg;
            if (r < N_NODES) out[r * 128 + nt * 16 + mrow] = f2h(acc[nt][rg] * ds[rg]);
        }
    }
}

// ---------------- CSR aggregation: 4 nodes/wave, depth-1 pipeline, predicated slots --------
// Per node: 6 predicated gather slots + self-loop issued in ONE shot; invalid slots point at
// the zero row h[ZROW] (adding +0.0h is exact => bit-identical accumulation order vs r0).
// Rare residual (deg > q+24, ~1-2% of quarters) handled in a slow loop at accumulate time.
// Wave pipelines node k+1's gathers + node k+2's index loads ahead of node k's accumulate:
// ~14 gather instrs (~14 KB) in flight per wave steady-state (vs 4 in the r0 kernel).

struct Ictx { int n; int grp; int s0, s1, s2, s3, s4, s5; };
struct Gt { uint4 t0, t1, t2, t3, t4, t5, slf; };

__device__ __forceinline__ Ictx idx_stage(const int* __restrict__ esrc, int off, int n, int q) {
    Ictx c; c.n = n;
    const int* ep = esrc + off;
    // unconditional loads: stay inside the workspace (overread lands in the next ws buffer)
    int r0 = ep[q], r1 = ep[q + 4], r2 = ep[q + 8];
    int r3 = ep[q + 12], r4 = ep[q + 16], r5 = ep[q + 20];
    bool grp = (q + 12 < n);
    bool ok = (n <= q + 24);
    c.grp = grp;
    c.s0 = (grp || q < n)      ? r0 : ZROW;
    c.s1 = (grp || q + 4 < n)  ? r1 : ZROW;
    c.s2 = (grp || q + 8 < n)  ? r2 : ZROW;
    c.s3 = grp                 ? r3 : ZROW;
    c.s4 = (grp && ok && q + 16 < n) ? r4 : ZROW;
    c.s5 = (grp && ok && q + 20 < n) ? r5 : ZROW;
    return c;
}

__device__ __forceinline__ Gt gather_stage(const Ictx& c, int v, int l,
                                           const uint4* __restrict__ h16) {
    Gt g;
    g.t0 = h16[(size_t)c.s0 * 16 + l];
    g.t1 = h16[(size_t)c.s1 * 16 + l];
    g.t2 = h16[(size_t)c.s2 * 16 + l];
    g.t3 = h16[(size_t)c.s3 * 16 + l];
    g.t4 = h16[(size_t)c.s4 * 16 + l];
    g.t5 = h16[(size_t)c.s5 * 16 + l];
    g.slf = h16[(size_t)v * 16 + l];
    return g;
}

__device__ __forceinline__ void acc_finish(const Gt& g, const Ictx& c, int v, int q, int l,
                                           const int* __restrict__ esrc, int off,
                                           const uint4* __restrict__ h16,
                                           float dsv, float4 b0, float4 b1,
                                           ushort* __restrict__ out) {
    uint4 aA = make_uint4(0, 0, 0, 0), aB = make_uint4(0, 0, 0, 0);
    // exact r0 order: group -> aA,aB,aA,aB ; singles -> aA (invalid slots add +0)
    aA = pk4(aA, g.t0);
    if (c.grp) aB = pk4(aB, g.t1); else aA = pk4(aA, g.t1);
    aA = pk4(aA, g.t2);
    if (c.grp) aB = pk4(aB, g.t3); else aA = pk4(aA, g.t3);
    aA = pk4(aA, g.t4);
    aA = pk4(aA, g.t5);
    if (c.n > q + 24) {  // rare residual: exact r0 continuation from i = q+16
        const int* ep = esrc + off;
        int i = q + 16;
        for (; i + 12 < c.n; i += 16) {
            uint4 u0 = h16[(size_t)ep[i] * 16 + l];
            uint4 u1 = h16[(size_t)ep[i + 4] * 16 + l];
            uint4 u2 = h16[(size_t)ep[i + 8] * 16 + l];
            uint4 u3 = h16[(size_t)ep[i + 12] * 16 + l];
            aA = pk4(aA, u0); aB = pk4(aB, u1); aA = pk4(aA, u2); aB = pk4(aB, u3);
        }
        for (; i < c.n; i += 4) aA = pk4(aA, h16[(size_t)ep[i] * 16 + l]);
    }
    aA = pk4(aA, aB);
    // reduce across the 4 quarters
    aA.x = pkadd(aA.x, (uint)__shfl_xor((int)aA.x, 16));
    aA.y = pkadd(aA.y, (uint)__shfl_xor((int)aA.y, 16));
    aA.z = pkadd(aA.z, (uint)__shfl_xor((int)aA.z, 16));
    aA.w = pkadd(aA.w, (uint)__shfl_xor((int)aA.w, 16));
    aA.x = pkadd(aA.x, (uint)__shfl_xor((int)aA.x, 32));
    aA.y = pkadd(aA.y, (uint)__shfl_xor((int)aA.y, 32));
    aA.z = pkadd(aA.z, (uint)__shfl_xor((int)aA.z, 32));
    aA.w = pkadd(aA.w, (uint)__shfl_xor((int)aA.w, 32));

    if (q == 0) {
        aA = pk4(aA, g.slf);  // self-loop term h'[v] (prefetched)
        float2 a0 = __half22float2(*(__half2*)&aA.x);
        float2 a1 = __half22float2(*(__half2*)&aA.y);
        float2 a2 = __half22float2(*(__half2*)&aA.z);
        float2 a3 = __half22float2(*(__half2*)&aA.w);
        a0.x = fmaxf(a0.x * dsv + b0.x, 0.f); a0.y = fmaxf(a0.y * dsv + b0.y, 0.f);
        a1.x = fmaxf(a1.x * dsv + b0.z, 0.f); a1.y = fmaxf(a1.y * dsv + b0.w, 0.f);
        a2.x = fmaxf(a2.x * dsv + b1.x, 0.f); a2.y = fmaxf(a2.y * dsv + b1.y, 0.f);
        a3.x = fmaxf(a3.x * dsv + b1.z, 0.f); a3.y = fmaxf(a3.y * dsv + b1.w, 0.f);
        __half2 o0 = __float22half2_rn(a0);
        __half2 o1 = __float22half2_rn(a1);
        __half2 o2 = __float22half2_rn(a2);
        __half2 o3 = __float22half2_rn(a3);
        ((uint4*)out)[v * 16 + l] =
            make_uint4(*(uint*)&o0, *(uint*)&o1, *(uint*)&o2, *(uint*)&o3);
    }
}

__global__ __launch_bounds__(256) void k_agg(const int2* __restrict__ scnt,
                                             const int* __restrict__ esrc,
                                             const ushort* __restrict__ h,
                                             const float* __restrict__ dis,
                                             const float* __restrict__ bias,
                                             ushort* __restrict__ out) {
    const int w = threadIdx.x >> 6;
    const int vb = blockIdx.x * 16 + w * 4;  // 4 nodes per wave; grid exact (100000 = 6250*16)
    const int lane = threadIdx.x & 63, q = lane >> 4, l = lane & 15;
    const uint4* h16 = (const uint4*)h;

    // one-RT preload of all per-node meta + wave constants
    int2 m0 = scnt[vb], m1 = scnt[vb + 1], m2 = scnt[vb + 2], m3 = scnt[vb + 3];
    float d0 = dis[vb], d1 = dis[vb + 1], d2 = dis[vb + 2], d3 = dis[vb + 3];
    float4 b0 = ((const float4*)bias)[2 * l];
    float4 b1 = ((const float4*)bias)[2 * l + 1];

    Ictx c0 = idx_stage(esrc, m0.x, m0.y, q);
    Gt g0 = gather_stage(c0, vb, l, h16);
    Ictx c1 = idx_stage(esrc, m1.x, m1.y, q);
    Gt g1 = gather_stage(c1, vb + 1, l, h16);
    Ictx c2 = idx_stage(esrc, m2.x, m2.y, q);
    acc_finish(g0, c0, vb, q, l, esrc, m0.x, h16, d0, b0, b1, out);
    Gt g2 = gather_stage(c2, vb + 2, l, h16);
    Ictx c3 = idx_stage(esrc, m3.x, m3.y, q);
    acc_finish(g1, c1, vb + 1, q, l, esrc, m1.x, h16, d1, b0, b1, out);
    Gt g3 = gather_stage(c3, vb + 3, l, h16);
    acc_finish(g2, c2, vb + 2, q, l, esrc, m2.x, h16, d2, b0, b1, out);
    acc_finish(g3, c3, vb + 3, q, l, esrc, m3.x, h16, d3, b0, b1, out);
}

// ---------------- final MFMA: out_f32[N][64] = (x1+x2)@Wo + bo (r6-proven) ----------------

__global__ __launch_bounds__(256) void k_final_mfma(const ushort* __restrict__ x1,
                                                    const ushort* __restrict__ x2,
                                                    const ushort* __restrict__ Ws,
                                                    const float* __restrict__ bo,
                                                    float* __restrict__ out) {
    __shared__ ushort sB[64 * 128];
    __shared__ ushort sA[64 * 128];
    const int tid = threadIdx.x;
    const int row0 = blockIdx.x * 64;

    for (int i = tid; i < 1024; i += 256)
        ((float4*)sB)[i] = ((const float4*)Ws)[i];

    for (int i = tid; i < 2048; i += 256) {
        int m = i >> 5, u = i & 31, k4 = u << 2;
        int r = row0 + m;
        uint2 pk = make_uint2(0, 0);
        if (r < N_NODES) {
            uint2 ua = ((const uint2*)x1)[r * 32 + u];
            uint2 ub = ((const uint2*)x2)[r * 32 + u];
            __half2 s0 = __hadd2(*(__half2*)&ua.x, *(__half2*)&ub.x);
            __half2 s1 = __hadd2(*(__half2*)&ua.y, *(__half2*)&ub.y);
            pk = make_uint2(*(uint*)&s0, *(uint*)&s1);
        }
        *(uint2*)&sA[swz(m, k4)] = pk;
    }
    __syncthreads();

    const int lane = tid & 63, wv = tid >> 6;
    const int mrow = lane & 15, quad = lane >> 4;
    f32x4 acc[4] = {};
#pragma unroll
    for (int kc = 0; kc < 4; ++kc) {
        int g = kc * 4 + quad;
        half8 a = *(const half8*)&sA[(wv * 16 + mrow) * 128 + ((g ^ mrow) << 3)];
#pragma unroll
        for (int nt = 0; nt < 4; ++nt) {
            half8 b = *(const half8*)&sB[(nt * 16 + mrow) * 128 + ((g ^ mrow) << 3)];
            acc[nt] = __builtin_amdgcn_mfma_f32_16x16x32_f16(a, b, acc[nt], 0, 0, 0);
        }
    }

    const int rbase = row0 + wv * 16 + quad * 4;
#pragma unroll
    for (int nt = 0; nt < 4; ++nt) {
        float bb = bo[nt * 16 + mrow];
#pragma unroll
        for (int rg = 0; rg < 4; ++rg) {
            int r = rbase + rg;
            if (r < N_NODES) out[(size_t)r * 64 + nt * 16 + mrow] = acc[nt][rg] + bb;
        }
    }
}

// ---------------- launch ----------------

extern "C" void kernel_launch(void* const* d_in, const int* in_sizes, int n_in,
                              void* d_out, int out_size, void* d_ws, size_t ws_size,
                              hipStream_t stream) {
    const float* x  = (const float*)d_in[0];
    const int*   ei = (const int*)d_in[1];
    const int*   src = ei;
    const int*   dst = ei + N_EDGES;
    const float* W1 = (const float*)d_in[2];
    const float* b1 = (const float*)d_in[3];
    const float* W2 = (const float*)d_in[4];
    const float* b2 = (const float*)d_in[5];
    const float* Wo = (const float*)d_in[6];
    const float* bo = (const float*)d_in[7];
    float* out = (float*)d_out;

    char* ws = (char*)d_ws;
    int*    bfill  = (int*)ws;            ws += 2048;
    int*    bbase  = (int*)ws;            ws += 2048;
    int2*   scnt   = (int2*)ws;           ws += 800000;                    // packed (start,cnt)
    float*  dis    = (float*)ws;          ws += 400000;
    int*    bin    = (int*)ws;            ws += (size_t)NBUCKET * CAP * 4; // 12.8 MB
    int*    esrc   = (int*)ws;            ws += (size_t)N_EDGES * 4;
    ushort* W1s    = (ushort*)ws;         ws += 32768;
    ushort* W2s    = (ushort*)ws;         ws += 32768;
    ushort* WoTs   = (ushort*)ws;         ws += 16384;
    ushort* h      = (ushort*)ws;         ws += (size_t)(N_NODES + 1) * CH * 2;  // +1 zero row
    ushort* x1     = (ushort*)ws;         ws += (size_t)N_NODES * CH * 2;
    ushort* x2     = (ushort*)ws;

    const int B = 256;
    const int gG = (N_NODES + 63) / 64;   // 1563
    const int gA = N_NODES / 16;          // 6250 (4 waves x 4 nodes per block)

    // CSR build (LDS-staged counting sort) + weight prep + zero row for predicated gathers
    hipMemsetAsync(bfill, 0, 2048, stream);
    hipMemsetAsync(h + (size_t)N_NODES * CH, 0, CH * 2, stream);
    k_bin<<<(N_EDGES + BIN_CHUNK - 1) / BIN_CHUNK, 512, 0, stream>>>(src, dst, bfill, bin);
    k_scan_prep<<<81, 512, 0, stream>>>(bfill, bbase, W1, W2, Wo, W1s, W2s, WoTs);
    k_build<<<NBUCKET, 256, 0, stream>>>(bfill, bbase, bin, esrc, scnt, dis);

    // layer 1
    k_gemm_mfma<float><<<gG, B, 0, stream>>>(x, W1s, dis, h);
    k_agg<<<gA, B, 0, stream>>>(scnt, esrc, h, dis, b1, x1);

    // layer 2
    k_gemm_mfma<ushort><<<gG, B, 0, stream>>>(x1, W2s, dis, h);
    k_agg<<<gA, B, 0, stream>>>(scnt, esrc, h, dis, b2, x2);

    // output projection
    k_final_mfma<<<gG, B, 0, stream>>>(x1, x2, WoTs, bo, out);
}

// Round 6
// 311.413 us; speedup vs baseline: 1.4210x; 1.0820x over previous
//
#include <hip/hip_runtime.h>
#include <hip/hip_fp16.h>

#define N_NODES 100000
#define N_EDGES 1600000
#define CH 128
#define OCH 64
#define NBUCKET 391   // ceil(100000/256) dst-buckets of 256 nodes
#define CAP 8192      // bucket capacity (mean 4092, sd ~64)
#define BIN_CHUNK 4096
#define ZROW N_NODES  // index of the guaranteed-zero h row (predication target)

typedef _Float16 half8 __attribute__((ext_vector_type(8)));
typedef float f32x4 __attribute__((ext_vector_type(4)));

__device__ __forceinline__ ushort f2h(float f) {
    _Float16 h = (_Float16)f;
    return *(ushort*)&h;
}

__device__ __forceinline__ uint pkadd(uint a, uint b) {
    __half2 r = __hadd2(*(__half2*)&a, *(__half2*)&b);
    return *(uint*)&r;
}

__device__ __forceinline__ uint4 pk4(uint4 a, uint4 b) {
    a.x = pkadd(a.x, b.x); a.y = pkadd(a.y, b.y);
    a.z = pkadd(a.z, b.z); a.w = pkadd(a.w, b.w);
    return a;
}

// XOR-swizzled f16 offset inside a [rows][128] f16 tile (r6-proven, 0 conflicts).
__device__ __forceinline__ int swz(int row, int k) {
    return row * 128 + ((((k >> 3) ^ (row & 15)) << 3) | (k & 7));
}

// ---------------- CSR build: LDS-staged counting sort (r6-proven shape) ----------------

__global__ __launch_bounds__(512) void k_bin(const int* __restrict__ src,
                                             const int* __restrict__ dst,
                                             int* __restrict__ bfill,
                                             int* __restrict__ bin) {
    __shared__ int hist[512];
    __shared__ int wbase[512];
    __shared__ int cur[512];
    const int t = threadIdx.x;
    const int e0 = blockIdx.x * BIN_CHUNK;

    hist[t] = 0;
    __syncthreads();

    int ss[8], bb[8], dl[8];
#pragma unroll
    for (int j = 0; j < 8; ++j) {
        int e = e0 + j * 512 + t;
        bb[j] = -1;
        if (e < N_EDGES) {
            int s = src[e], d = dst[e];
            ss[j] = s; dl[j] = d & 255; bb[j] = d >> 8;
            atomicAdd(&hist[bb[j]], 1);
        }
    }
    __syncthreads();

    int v = hist[t];
    for (int off = 1; off < 512; off <<= 1) {
        int tv = (t >= off) ? hist[t - off] : 0;
        __syncthreads();
        hist[t] += tv;
        __syncthreads();
    }
    int excl = hist[t] - v;
    if (t < NBUCKET && v > 0) {
        int gb = atomicAdd(&bfill[t], v);
        wbase[t] = gb - excl;
    }
    cur[t] = excl;
    __syncthreads();

#pragma unroll
    for (int j = 0; j < 8; ++j) {
        if (bb[j] >= 0) {
            int p = atomicAdd(&cur[bb[j]], 1);
            bin[bb[j] * CAP + wbase[bb[j]] + p] = (ss[j] << 8) | dl[j];
        }
    }
}

// block 0: exclusive scan of bucket fills. blocks 1..80: weight prep. block 81: zero row.
__global__ __launch_bounds__(512) void k_scan_prep(const int* __restrict__ bfill,
                                                   int* __restrict__ bbase,
                                                   const float* __restrict__ W1,
                                                   const float* __restrict__ W2,
                                                   const float* __restrict__ Wo,
                                                   ushort* __restrict__ W1s,
                                                   ushort* __restrict__ W2s,
                                                   ushort* __restrict__ WoTs,
                                                   ushort* __restrict__ h) {
    if (blockIdx.x == 0) {
        __shared__ int tmp[512];
        int t = threadIdx.x;
        int v = (t < NBUCKET) ? bfill[t] : 0;
        tmp[t] = v;
        __syncthreads();
        for (int off = 1; off < 512; off <<= 1) {
            int tv = (t >= off) ? tmp[t - off] : 0;
            __syncthreads();
            tmp[t] += tv;
            __syncthreads();
        }
        if (t < NBUCKET) bbase[t] = tmp[t] - v;
    } else if (blockIdx.x == 81) {
        if (threadIdx.x < CH) h[(size_t)ZROW * CH + threadIdx.x] = 0;  // zero row for k_agg
    } else {
        int i = (blockIdx.x - 1) * 512 + threadIdx.x;  // 0..40959
        if (i < 16384) {
            int k = i >> 7, n = i & 127;
            W1s[swz(n, k)] = f2h(W1[i]);
        } else if (i < 32768) {
            int j = i - 16384, k = j >> 7, n = j & 127;
            W2s[swz(n, k)] = f2h(W2[j]);
        } else if (i < 40960) {
            int j = i - 32768, k = j >> 6, n = j & 63;
            WoTs[swz(n, k)] = f2h(Wo[j]);
        }
    }
}

__global__ __launch_bounds__(256) void k_build(const int* __restrict__ bfill,
                                               const int* __restrict__ bbase,
                                               const int* __restrict__ bin,
                                               int* __restrict__ esrc,
                                               int2* __restrict__ scnt,
                                               float* __restrict__ dis) {
    __shared__ int cnt_l[256];
    __shared__ int cur_l[256];
    __shared__ int sortbuf[CAP];
    const int t = threadIdx.x;
    const int b = blockIdx.x;
    const int n = bfill[b];
    const int base = bbase[b];
    const int* brec = bin + b * CAP;

    cnt_l[t] = 0;
    __syncthreads();
    for (int i = t; i < n; i += 256)
        atomicAdd(&cnt_l[brec[i] & 255], 1);
    __syncthreads();

    int v = cnt_l[t];
    for (int off = 1; off < 256; off <<= 1) {
        int tv = (t >= off) ? cnt_l[t - off] : 0;
        __syncthreads();
        cnt_l[t] += tv;
        __syncthreads();
    }
    int excl = cnt_l[t] - v;
    int node = b * 256 + t;
    if (node < N_NODES) {
        scnt[node] = make_int2(base + excl, v);
        dis[node] = rsqrtf((float)(v + 1));  // +1 self-loop
    }
    cur_l[t] = excl;
    __syncthreads();

    for (int i = t; i < n; i += 256) {
        int rec = brec[i];
        int p = atomicAdd(&cur_l[rec & 255], 1);
        sortbuf[p] = rec >> 8;
    }
    __syncthreads();
    for (int i = t; i < n; i += 256)
        esrc[base + i] = sortbuf[i];
}

// ---------------- MFMA GEMM: out_f16[r] = dis[r] * (A[r] @ W) ----------------
// Epilogue: LDS-bounce transpose (padded [64][136] tile) -> 4 coalesced uint4
// stores per thread, replacing 32 scattered 2-byte stores (values bit-identical).

template <typename IT>
__global__ __launch_bounds__(256) void k_gemm_mfma(const IT* __restrict__ A,
                                                   const ushort* __restrict__ Ws,
                                                   const float* __restrict__ dis,
                                                   ushort* __restrict__ out) {
    __shared__ ushort sB[128 * 128];
    __shared__ ushort sA[64 * 136];   // MFMA phase uses [64][128] region; epilogue re-uses padded
    const int tid = threadIdx.x;
    const int row0 = blockIdx.x * 64;

    for (int i = tid; i < 2048; i += 256)
        ((float4*)sB)[i] = ((const float4*)Ws)[i];

    for (int i = tid; i < 2048; i += 256) {
        int m = i >> 5, u = i & 31, k4 = u << 2;
        int r = row0 + m;
        ushort4 pk = make_ushort4(0, 0, 0, 0);
        if (r < N_NODES) {
            if constexpr (sizeof(IT) == 4) {
                float4 a = ((const float4*)A)[r * 32 + u];
                pk = make_ushort4(f2h(a.x), f2h(a.y), f2h(a.z), f2h(a.w));
            } else {
                pk = ((const ushort4*)A)[r * 32 + u];
            }
        }
        *(ushort4*)&sA[swz(m, k4)] = pk;
    }
    __syncthreads();

    const int lane = tid & 63, wv = tid >> 6;
    const int mrow = lane & 15, quad = lane >> 4;
    f32x4 acc[8] = {};
#pragma unroll
    for (int kc = 0; kc < 4; ++kc) {
        int g = kc * 4 + quad;
        half8 a = *(const half8*)&sA[(wv * 16 + mrow) * 128 + ((g ^ mrow) << 3)];
#pragma unroll
        for (int nt = 0; nt < 8; ++nt) {
            half8 b = *(const half8*)&sB[(nt * 16 + mrow) * 128 + ((g ^ mrow) << 3)];
            acc[nt] = __builtin_amdgcn_mfma_f32_16x16x32_f16(a, b, acc[nt], 0, 0, 0);
        }
    }

    const int rbase4 = wv * 16 + quad * 4;  // local row of this lane's 4-row group
    float ds[4];
#pragma unroll
    for (int rg = 0; rg < 4; ++rg)
        ds[rg] = (row0 + rbase4 + rg < N_NODES) ? dis[row0 + rbase4 + rg] : 0.f;

    __syncthreads();  // all waves done reading sA/sB
#pragma unroll
    for (int nt = 0; nt < 8; ++nt) {
#pragma unroll
        for (int rg = 0; rg < 4; ++rg)
            sA[(rbase4 + rg) * 136 + nt * 16 + mrow] = f2h(acc[nt][rg] * ds[rg]);
    }
    __syncthreads();

    // coalesced write-out: 1024 uint4 chunks; chunk idx -> (row, 16B-chunk)
#pragma unroll
    for (int k = 0; k < 4; ++k) {
        int idx = tid + k * 256;
        int m = idx >> 4, c16 = idx & 15;
        int r = row0 + m;
        if (r < N_NODES) {
            uint4 vv = *(const uint4*)&sA[m * 136 + c16 * 8];
            ((uint4*)out)[(size_t)r * 16 + c16] = vv;
        }
    }
}

// ---------------- CSR aggregation: 4 nodes/wave, depth-1 pipeline, predicated slots --------
// (r5-proven: 61.5 us, saturates the ~3.5 TB/s miss-path service rate)

struct Ictx { int n; int grp; int s0, s1, s2, s3, s4, s5; };
struct Gt { uint4 t0, t1, t2, t3, t4, t5, slf; };

__device__ __forceinline__ Ictx idx_stage(const int* __restrict__ esrc, int off, int n, int q) {
    Ictx c; c.n = n;
    const int* ep = esrc + off;
    // unconditional loads: stay inside the workspace (overread lands in the next ws buffer)
    int r0 = ep[q], r1 = ep[q + 4], r2 = ep[q + 8];
    int r3 = ep[q + 12], r4 = ep[q + 16], r5 = ep[q + 20];
    bool grp = (q + 12 < n);
    bool ok = (n <= q + 24);
    c.grp = grp;
    c.s0 = (grp || q < n)      ? r0 : ZROW;
    c.s1 = (grp || q + 4 < n)  ? r1 : ZROW;
    c.s2 = (grp || q + 8 < n)  ? r2 : ZROW;
    c.s3 = grp                 ? r3 : ZROW;
    c.s4 = (grp && ok && q + 16 < n) ? r4 : ZROW;
    c.s5 = (grp && ok && q + 20 < n) ? r5 : ZROW;
    return c;
}

__device__ __forceinline__ Gt gather_stage(const Ictx& c, int v, int l,
                                           const uint4* __restrict__ h16) {
    Gt g;
    g.t0 = h16[(size_t)c.s0 * 16 + l];
    g.t1 = h16[(size_t)c.s1 * 16 + l];
    g.t2 = h16[(size_t)c.s2 * 16 + l];
    g.t3 = h16[(size_t)c.s3 * 16 + l];
    g.t4 = h16[(size_t)c.s4 * 16 + l];
    g.t5 = h16[(size_t)c.s5 * 16 + l];
    g.slf = h16[(size_t)v * 16 + l];
    return g;
}

__device__ __forceinline__ void acc_finish(const Gt& g, const Ictx& c, int v, int q, int l,
                                           const int* __restrict__ esrc, int off,
                                           const uint4* __restrict__ h16,
                                           float dsv, float4 b0, float4 b1,
                                           ushort* __restrict__ out) {
    uint4 aA = make_uint4(0, 0, 0, 0), aB = make_uint4(0, 0, 0, 0);
    // exact r0 order: group -> aA,aB,aA,aB ; singles -> aA (invalid slots add +0)
    aA = pk4(aA, g.t0);
    if (c.grp) aB = pk4(aB, g.t1); else aA = pk4(aA, g.t1);
    aA = pk4(aA, g.t2);
    if (c.grp) aB = pk4(aB, g.t3); else aA = pk4(aA, g.t3);
    aA = pk4(aA, g.t4);
    aA = pk4(aA, g.t5);
    if (c.n > q + 24) {  // rare residual: exact r0 continuation from i = q+16
        const int* ep = esrc + off;
        int i = q + 16;
        for (; i + 12 < c.n; i += 16) {
            uint4 u0 = h16[(size_t)ep[i] * 16 + l];
            uint4 u1 = h16[(size_t)ep[i + 4] * 16 + l];
            uint4 u2 = h16[(size_t)ep[i + 8] * 16 + l];
            uint4 u3 = h16[(size_t)ep[i + 12] * 16 + l];
            aA = pk4(aA, u0); aB = pk4(aB, u1); aA = pk4(aA, u2); aB = pk4(aB, u3);
        }
        for (; i < c.n; i += 4) aA = pk4(aA, h16[(size_t)ep[i] * 16 + l]);
    }
    aA = pk4(aA, aB);
    // reduce across the 4 quarters
    aA.x = pkadd(aA.x, (uint)__shfl_xor((int)aA.x, 16));
    aA.y = pkadd(aA.y, (uint)__shfl_xor((int)aA.y, 16));
    aA.z = pkadd(aA.z, (uint)__shfl_xor((int)aA.z, 16));
    aA.w = pkadd(aA.w, (uint)__shfl_xor((int)aA.w, 16));
    aA.x = pkadd(aA.x, (uint)__shfl_xor((int)aA.x, 32));
    aA.y = pkadd(aA.y, (uint)__shfl_xor((int)aA.y, 32));
    aA.z = pkadd(aA.z, (uint)__shfl_xor((int)aA.z, 32));
    aA.w = pkadd(aA.w, (uint)__shfl_xor((int)aA.w, 32));

    if (q == 0) {
        aA = pk4(aA, g.slf);  // self-loop term h'[v] (prefetched)
        float2 a0 = __half22float2(*(__half2*)&aA.x);
        float2 a1 = __half22float2(*(__half2*)&aA.y);
        float2 a2 = __half22float2(*(__half2*)&aA.z);
        float2 a3 = __half22float2(*(__half2*)&aA.w);
        a0.x = fmaxf(a0.x * dsv + b0.x, 0.f); a0.y = fmaxf(a0.y * dsv + b0.y, 0.f);
        a1.x = fmaxf(a1.x * dsv + b0.z, 0.f); a1.y = fmaxf(a1.y * dsv + b0.w, 0.f);
        a2.x = fmaxf(a2.x * dsv + b1.x, 0.f); a2.y = fmaxf(a2.y * dsv + b1.y, 0.f);
        a3.x = fmaxf(a3.x * dsv + b1.z, 0.f); a3.y = fmaxf(a3.y * dsv + b1.w, 0.f);
        __half2 o0 = __float22half2_rn(a0);
        __half2 o1 = __float22half2_rn(a1);
        __half2 o2 = __float22half2_rn(a2);
        __half2 o3 = __float22half2_rn(a3);
        ((uint4*)out)[v * 16 + l] =
            make_uint4(*(uint*)&o0, *(uint*)&o1, *(uint*)&o2, *(uint*)&o3);
    }
}

__global__ __launch_bounds__(256) void k_agg(const int2* __restrict__ scnt,
                                             const int* __restrict__ esrc,
                                             const ushort* __restrict__ h,
                                             const float* __restrict__ dis,
                                             const float* __restrict__ bias,
                                             ushort* __restrict__ out) {
    const int w = threadIdx.x >> 6;
    const int vb = blockIdx.x * 16 + w * 4;  // 4 nodes per wave; grid exact (100000 = 6250*16)
    const int lane = threadIdx.x & 63, q = lane >> 4, l = lane & 15;
    const uint4* h16 = (const uint4*)h;

    // one-RT preload of all per-node meta + wave constants
    int2 m0 = scnt[vb], m1 = scnt[vb + 1], m2 = scnt[vb + 2], m3 = scnt[vb + 3];
    float d0 = dis[vb], d1 = dis[vb + 1], d2 = dis[vb + 2], d3 = dis[vb + 3];
    float4 b0 = ((const float4*)bias)[2 * l];
    float4 b1 = ((const float4*)bias)[2 * l + 1];

    Ictx c0 = idx_stage(esrc, m0.x, m0.y, q);
    Gt g0 = gather_stage(c0, vb, l, h16);
    Ictx c1 = idx_stage(esrc, m1.x, m1.y, q);
    Gt g1 = gather_stage(c1, vb + 1, l, h16);
    Ictx c2 = idx_stage(esrc, m2.x, m2.y, q);
    acc_finish(g0, c0, vb, q, l, esrc, m0.x, h16, d0, b0, b1, out);
    Gt g2 = gather_stage(c2, vb + 2, l, h16);
    Ictx c3 = idx_stage(esrc, m3.x, m3.y, q);
    acc_finish(g1, c1, vb + 1, q, l, esrc, m1.x, h16, d1, b0, b1, out);
    Gt g3 = gather_stage(c3, vb + 3, l, h16);
    acc_finish(g2, c2, vb + 2, q, l, esrc, m2.x, h16, d2, b0, b1, out);
    acc_finish(g3, c3, vb + 3, q, l, esrc, m3.x, h16, d3, b0, b1, out);
}

// ---------------- final MFMA: out_f32[N][64] = (x1+x2)@Wo + bo (r6-proven) ----------------

__global__ __launch_bounds__(256) void k_final_mfma(const ushort* __restrict__ x1,
                                                    const ushort* __restrict__ x2,
                                                    const ushort* __restrict__ Ws,
                                                    const float* __restrict__ bo,
                                                    float* __restrict__ out) {
    __shared__ ushort sB[64 * 128];
    __shared__ ushort sA[64 * 128];
    const int tid = threadIdx.x;
    const int row0 = blockIdx.x * 64;

    for (int i = tid; i < 1024; i += 256)
        ((float4*)sB)[i] = ((const float4*)Ws)[i];

    for (int i = tid; i < 2048; i += 256) {
        int m = i >> 5, u = i & 31, k4 = u << 2;
        int r = row0 + m;
        uint2 pk = make_uint2(0, 0);
        if (r < N_NODES) {
            uint2 ua = ((const uint2*)x1)[r * 32 + u];
            uint2 ub = ((const uint2*)x2)[r * 32 + u];
            __half2 s0 = __hadd2(*(__half2*)&ua.x, *(__half2*)&ub.x);
            __half2 s1 = __hadd2(*(__half2*)&ua.y, *(__half2*)&ub.y);
            pk = make_uint2(*(uint*)&s0, *(uint*)&s1);
        }
        *(uint2*)&sA[swz(m, k4)] = pk;
    }
    __syncthreads();

    const int lane = tid & 63, wv = tid >> 6;
    const int mrow = lane & 15, quad = lane >> 4;
    f32x4 acc[4] = {};
#pragma unroll
    for (int kc = 0; kc < 4; ++kc) {
        int g = kc * 4 + quad;
        half8 a = *(const half8*)&sA[(wv * 16 + mrow) * 128 + ((g ^ mrow) << 3)];
#pragma unroll
        for (int nt = 0; nt < 4; ++nt) {
            half8 b = *(const half8*)&sB[(nt * 16 + mrow) * 128 + ((g ^ mrow) << 3)];
            acc[nt] = __builtin_amdgcn_mfma_f32_16x16x32_f16(a, b, acc[nt], 0, 0, 0);
        }
    }

    const int rbase = row0 + wv * 16 + quad * 4;
#pragma unroll
    for (int nt = 0; nt < 4; ++nt) {
        float bb = bo[nt * 16 + mrow];
#pragma unroll
        for (int rg = 0; rg < 4; ++rg) {
            int r = rbase + rg;
            if (r < N_NODES) out[(size_t)r * 64 + nt * 16 + mrow] = acc[nt][rg] + bb;
        }
    }
}

// ---------------- launch ----------------

extern "C" void kernel_launch(void* const* d_in, const int* in_sizes, int n_in,
                              void* d_out, int out_size, void* d_ws, size_t ws_size,
                              hipStream_t stream) {
    const float* x  = (const float*)d_in[0];
    const int*   ei = (const int*)d_in[1];
    const int*   src = ei;
    const int*   dst = ei + N_EDGES;
    const float* W1 = (const float*)d_in[2];
    const float* b1 = (const float*)d_in[3];
    const float* W2 = (const float*)d_in[4];
    const float* b2 = (const float*)d_in[5];
    const float* Wo = (const float*)d_in[6];
    const float* bo = (const float*)d_in[7];
    float* out = (float*)d_out;

    char* ws = (char*)d_ws;
    int*    bfill  = (int*)ws;            ws += 2048;
    int*    bbase  = (int*)ws;            ws += 2048;
    int2*   scnt   = (int2*)ws;           ws += 800000;                    // packed (start,cnt)
    float*  dis    = (float*)ws;          ws += 400000;
    int*    bin    = (int*)ws;            ws += (size_t)NBUCKET * CAP * 4; // 12.8 MB
    int*    esrc   = (int*)ws;            ws += (size_t)N_EDGES * 4;
    ushort* W1s    = (ushort*)ws;         ws += 32768;
    ushort* W2s    = (ushort*)ws;         ws += 32768;
    ushort* WoTs   = (ushort*)ws;         ws += 16384;
    ushort* h      = (ushort*)ws;         ws += (size_t)(N_NODES + 1) * CH * 2;  // +1 zero row
    ushort* x1     = (ushort*)ws;         ws += (size_t)N_NODES * CH * 2;
    ushort* x2     = (ushort*)ws;

    const int B = 256;
    const int gG = (N_NODES + 63) / 64;   // 1563
    const int gA = N_NODES / 16;          // 6250 (4 waves x 4 nodes per block)

    // CSR build (LDS-staged counting sort) + weight prep (+ zero row in scan_prep)
    hipMemsetAsync(bfill, 0, 2048, stream);
    k_bin<<<(N_EDGES + BIN_CHUNK - 1) / BIN_CHUNK, 512, 0, stream>>>(src, dst, bfill, bin);
    k_scan_prep<<<82, 512, 0, stream>>>(bfill, bbase, W1, W2, Wo, W1s, W2s, WoTs, h);
    k_build<<<NBUCKET, 256, 0, stream>>>(bfill, bbase, bin, esrc, scnt, dis);

    // layer 1
    k_gemm_mfma<float><<<gG, B, 0, stream>>>(x, W1s, dis, h);
    k_agg<<<gA, B, 0, stream>>>(scnt, esrc, h, dis, b1, x1);

    // layer 2
    k_gemm_mfma<ushort><<<gG, B, 0, stream>>>(x1, W2s, dis, h);
    k_agg<<<gA, B, 0, stream>>>(scnt, esrc, h, dis, b2, x2);

    // output projection
    k_final_mfma<<<gG, B, 0, stream>>>(x1, x2, WoTs, bo, out);
}

// Round 7
// 309.013 us; speedup vs baseline: 1.4320x; 1.0078x over previous
//
#include <hip/hip_runtime.h>
#include <hip/hip_fp16.h>

#define N_NODES 100000
#define N_EDGES 1600000
#define CH 128
#define OCH 64
#define NBUCKET 391   // ceil(100000/256) dst-buckets of 256 nodes
#define CAP 8192      // bucket capacity (mean 4092, sd ~64)
#define BIN_CHUNK 4096
#define ZROW N_NODES  // index of the guaranteed-zero h row (predication target)

typedef _Float16 half8 __attribute__((ext_vector_type(8)));
typedef float f32x4 __attribute__((ext_vector_type(4)));

__device__ __forceinline__ ushort f2h(float f) {
    _Float16 h = (_Float16)f;
    return *(ushort*)&h;
}

__device__ __forceinline__ uint pkadd(uint a, uint b) {
    __half2 r = __hadd2(*(__half2*)&a, *(__half2*)&b);
    return *(uint*)&r;
}

__device__ __forceinline__ uint4 pk4(uint4 a, uint4 b) {
    a.x = pkadd(a.x, b.x); a.y = pkadd(a.y, b.y);
    a.z = pkadd(a.z, b.z); a.w = pkadd(a.w, b.w);
    return a;
}

// XOR-swizzled f16 offset inside a [rows][128] f16 tile (r6-proven, 0 conflicts).
__device__ __forceinline__ int swz(int row, int k) {
    return row * 128 + ((((k >> 3) ^ (row & 15)) << 3) | (k & 7));
}

// ---------------- CSR build: LDS-staged counting sort (r6-proven shape) ----------------

__global__ __launch_bounds__(512) void k_bin(const int* __restrict__ src,
                                             const int* __restrict__ dst,
                                             int* __restrict__ bfill,
                                             int* __restrict__ bin) {
    __shared__ int hist[512];
    __shared__ int wbase[512];
    __shared__ int cur[512];
    const int t = threadIdx.x;
    const int e0 = blockIdx.x * BIN_CHUNK;

    hist[t] = 0;
    __syncthreads();

    int ss[8], bb[8], dl[8];
#pragma unroll
    for (int j = 0; j < 8; ++j) {
        int e = e0 + j * 512 + t;
        bb[j] = -1;
        if (e < N_EDGES) {
            int s = src[e], d = dst[e];
            ss[j] = s; dl[j] = d & 255; bb[j] = d >> 8;
            atomicAdd(&hist[bb[j]], 1);
        }
    }
    __syncthreads();

    int v = hist[t];
    for (int off = 1; off < 512; off <<= 1) {
        int tv = (t >= off) ? hist[t - off] : 0;
        __syncthreads();
        hist[t] += tv;
        __syncthreads();
    }
    int excl = hist[t] - v;
    if (t < NBUCKET && v > 0) {
        int gb = atomicAdd(&bfill[t], v);
        wbase[t] = gb - excl;
    }
    cur[t] = excl;
    __syncthreads();

#pragma unroll
    for (int j = 0; j < 8; ++j) {
        if (bb[j] >= 0) {
            int p = atomicAdd(&cur[bb[j]], 1);
            bin[bb[j] * CAP + wbase[bb[j]] + p] = (ss[j] << 8) | dl[j];
        }
    }
}

// block 0: exclusive scan of bucket fills. blocks 1..80: weight prep. block 81: zero row.
__global__ __launch_bounds__(512) void k_scan_prep(const int* __restrict__ bfill,
                                                   int* __restrict__ bbase,
                                                   const float* __restrict__ W1,
                                                   const float* __restrict__ W2,
                                                   const float* __restrict__ Wo,
                                                   ushort* __restrict__ W1s,
                                                   ushort* __restrict__ W2s,
                                                   ushort* __restrict__ WoTs,
                                                   ushort* __restrict__ h) {
    if (blockIdx.x == 0) {
        __shared__ int tmp[512];
        int t = threadIdx.x;
        int v = (t < NBUCKET) ? bfill[t] : 0;
        tmp[t] = v;
        __syncthreads();
        for (int off = 1; off < 512; off <<= 1) {
            int tv = (t >= off) ? tmp[t - off] : 0;
            __syncthreads();
            tmp[t] += tv;
            __syncthreads();
        }
        if (t < NBUCKET) bbase[t] = tmp[t] - v;
    } else if (blockIdx.x == 81) {
        if (threadIdx.x < CH) h[(size_t)ZROW * CH + threadIdx.x] = 0;  // zero row for k_agg
    } else {
        int i = (blockIdx.x - 1) * 512 + threadIdx.x;  // 0..40959
        if (i < 16384) {
            int k = i >> 7, n = i & 127;
            W1s[swz(n, k)] = f2h(W1[i]);
        } else if (i < 32768) {
            int j = i - 16384, k = j >> 7, n = j & 127;
            W2s[swz(n, k)] = f2h(W2[j]);
        } else if (i < 40960) {
            int j = i - 32768, k = j >> 6, n = j & 63;
            WoTs[swz(n, k)] = f2h(Wo[j]);
        }
    }
}

__global__ __launch_bounds__(256) void k_build(const int* __restrict__ bfill,
                                               const int* __restrict__ bbase,
                                               const int* __restrict__ bin,
                                               int* __restrict__ esrc,
                                               int2* __restrict__ scnt,
                                               float* __restrict__ dis) {
    __shared__ int cnt_l[256];
    __shared__ int cur_l[256];
    __shared__ int sortbuf[CAP];
    const int t = threadIdx.x;
    const int b = blockIdx.x;
    const int n = bfill[b];
    const int base = bbase[b];
    const int* brec = bin + b * CAP;

    cnt_l[t] = 0;
    __syncthreads();
    for (int i = t; i < n; i += 256)
        atomicAdd(&cnt_l[brec[i] & 255], 1);
    __syncthreads();

    int v = cnt_l[t];
    for (int off = 1; off < 256; off <<= 1) {
        int tv = (t >= off) ? cnt_l[t - off] : 0;
        __syncthreads();
        cnt_l[t] += tv;
        __syncthreads();
    }
    int excl = cnt_l[t] - v;
    int node = b * 256 + t;
    if (node < N_NODES) {
        scnt[node] = make_int2(base + excl, v);
        dis[node] = rsqrtf((float)(v + 1));  // +1 self-loop
    }
    cur_l[t] = excl;
    __syncthreads();

    for (int i = t; i < n; i += 256) {
        int rec = brec[i];
        int p = atomicAdd(&cur_l[rec & 255], 1);
        sortbuf[p] = rec >> 8;
    }
    __syncthreads();
    for (int i = t; i < n; i += 256)
        esrc[base + i] = sortbuf[i];
}

// ---------------- MFMA GEMM: out_f16[r] = dis[r] * (A[r] @ W) ----------------
// 128 rows/block, 512 threads (8 waves x 16 rows): halves weight-staging traffic,
// barriers and block count vs the 64-row version. Epilogue: LDS-bounce (padded
// [128][136]) -> 4 coalesced uint4 stores per thread. Values bit-identical.

template <typename IT>
__global__ __launch_bounds__(512) void k_gemm_mfma(const IT* __restrict__ A,
                                                   const ushort* __restrict__ Ws,
                                                   const float* __restrict__ dis,
                                                   ushort* __restrict__ out) {
    __shared__ ushort sB[128 * 128];   // 32 KB
    __shared__ ushort sA[128 * 136];   // 34.8 KB; MFMA phase uses stride-128 region
    const int tid = threadIdx.x;
    const int row0 = blockIdx.x * 128;

    for (int i = tid; i < 2048; i += 512)
        ((float4*)sB)[i] = ((const float4*)Ws)[i];

    for (int i = tid; i < 4096; i += 512) {
        int m = i >> 5, u = i & 31, k4 = u << 2;
        int r = row0 + m;
        ushort4 pk = make_ushort4(0, 0, 0, 0);
        if (r < N_NODES) {
            if constexpr (sizeof(IT) == 4) {
                float4 a = ((const float4*)A)[r * 32 + u];
                pk = make_ushort4(f2h(a.x), f2h(a.y), f2h(a.z), f2h(a.w));
            } else {
                pk = ((const ushort4*)A)[r * 32 + u];
            }
        }
        *(ushort4*)&sA[swz(m, k4)] = pk;
    }
    __syncthreads();

    const int lane = tid & 63, wv = tid >> 6;        // wv 0..7 -> rows wv*16..wv*16+15
    const int mrow = lane & 15, quad = lane >> 4;
    f32x4 acc[8] = {};
#pragma unroll
    for (int kc = 0; kc < 4; ++kc) {
        int g = kc * 4 + quad;
        half8 a = *(const half8*)&sA[(wv * 16 + mrow) * 128 + ((g ^ mrow) << 3)];
#pragma unroll
        for (int nt = 0; nt < 8; ++nt) {
            half8 b = *(const half8*)&sB[(nt * 16 + mrow) * 128 + ((g ^ mrow) << 3)];
            acc[nt] = __builtin_amdgcn_mfma_f32_16x16x32_f16(a, b, acc[nt], 0, 0, 0);
        }
    }

    const int rbase4 = wv * 16 + quad * 4;  // local row of this lane's 4-row group
    float ds[4];
#pragma unroll
    for (int rg = 0; rg < 4; ++rg)
        ds[rg] = (row0 + rbase4 + rg < N_NODES) ? dis[row0 + rbase4 + rg] : 0.f;

    __syncthreads();  // all waves done reading sA/sB
#pragma unroll
    for (int nt = 0; nt < 8; ++nt) {
#pragma unroll
        for (int rg = 0; rg < 4; ++rg)
            sA[(rbase4 + rg) * 136 + nt * 16 + mrow] = f2h(acc[nt][rg] * ds[rg]);
    }
    __syncthreads();

    // coalesced write-out: 2048 uint4 chunks; chunk idx -> (row, 16B-chunk)
#pragma unroll
    for (int k = 0; k < 4; ++k) {
        int idx = tid + k * 512;
        int m = idx >> 4, c16 = idx & 15;
        int r = row0 + m;
        if (r < N_NODES) {
            uint4 vv = *(const uint4*)&sA[m * 136 + c16 * 8];
            ((uint4*)out)[(size_t)r * 16 + c16] = vv;
        }
    }
}

// ---------------- CSR aggregation: 4 nodes/wave, depth-1 pipeline, predicated slots --------
// (r5-proven: 61.5 us, saturates the ~3.5 TB/s miss-path service rate)

struct Ictx { int n; int grp; int s0, s1, s2, s3, s4, s5; };
struct Gt { uint4 t0, t1, t2, t3, t4, t5, slf; };

__device__ __forceinline__ Ictx idx_stage(const int* __restrict__ esrc, int off, int n, int q) {
    Ictx c; c.n = n;
    const int* ep = esrc + off;
    // unconditional loads: stay inside the workspace (overread lands in the next ws buffer)
    int r0 = ep[q], r1 = ep[q + 4], r2 = ep[q + 8];
    int r3 = ep[q + 12], r4 = ep[q + 16], r5 = ep[q + 20];
    bool grp = (q + 12 < n);
    bool ok = (n <= q + 24);
    c.grp = grp;
    c.s0 = (grp || q < n)      ? r0 : ZROW;
    c.s1 = (grp || q + 4 < n)  ? r1 : ZROW;
    c.s2 = (grp || q + 8 < n)  ? r2 : ZROW;
    c.s3 = grp                 ? r3 : ZROW;
    c.s4 = (grp && ok && q + 16 < n) ? r4 : ZROW;
    c.s5 = (grp && ok && q + 20 < n) ? r5 : ZROW;
    return c;
}

__device__ __forceinline__ Gt gather_stage(const Ictx& c, int v, int l,
                                           const uint4* __restrict__ h16) {
    Gt g;
    g.t0 = h16[(size_t)c.s0 * 16 + l];
    g.t1 = h16[(size_t)c.s1 * 16 + l];
    g.t2 = h16[(size_t)c.s2 * 16 + l];
    g.t3 = h16[(size_t)c.s3 * 16 + l];
    g.t4 = h16[(size_t)c.s4 * 16 + l];
    g.t5 = h16[(size_t)c.s5 * 16 + l];
    g.slf = h16[(size_t)v * 16 + l];
    return g;
}

__device__ __forceinline__ void acc_finish(const Gt& g, const Ictx& c, int v, int q, int l,
                                           const int* __restrict__ esrc, int off,
                                           const uint4* __restrict__ h16,
                                           float dsv, float4 b0, float4 b1,
                                           ushort* __restrict__ out) {
    uint4 aA = make_uint4(0, 0, 0, 0), aB = make_uint4(0, 0, 0, 0);
    // exact r0 order: group -> aA,aB,aA,aB ; singles -> aA (invalid slots add +0)
    aA = pk4(aA, g.t0);
    if (c.grp) aB = pk4(aB, g.t1); else aA = pk4(aA, g.t1);
    aA = pk4(aA, g.t2);
    if (c.grp) aB = pk4(aB, g.t3); else aA = pk4(aA, g.t3);
    aA = pk4(aA, g.t4);
    aA = pk4(aA, g.t5);
    if (c.n > q + 24) {  // rare residual: exact r0 continuation from i = q+16
        const int* ep = esrc + off;
        int i = q + 16;
        for (; i + 12 < c.n; i += 16) {
            uint4 u0 = h16[(size_t)ep[i] * 16 + l];
            uint4 u1 = h16[(size_t)ep[i + 4] * 16 + l];
            uint4 u2 = h16[(size_t)ep[i + 8] * 16 + l];
            uint4 u3 = h16[(size_t)ep[i + 12] * 16 + l];
            aA = pk4(aA, u0); aB = pk4(aB, u1); aA = pk4(aA, u2); aB = pk4(aB, u3);
        }
        for (; i < c.n; i += 4) aA = pk4(aA, h16[(size_t)ep[i] * 16 + l]);
    }
    aA = pk4(aA, aB);
    // reduce across the 4 quarters
    aA.x = pkadd(aA.x, (uint)__shfl_xor((int)aA.x, 16));
    aA.y = pkadd(aA.y, (uint)__shfl_xor((int)aA.y, 16));
    aA.z = pkadd(aA.z, (uint)__shfl_xor((int)aA.z, 16));
    aA.w = pkadd(aA.w, (uint)__shfl_xor((int)aA.w, 16));
    aA.x = pkadd(aA.x, (uint)__shfl_xor((int)aA.x, 32));
    aA.y = pkadd(aA.y, (uint)__shfl_xor((int)aA.y, 32));
    aA.z = pkadd(aA.z, (uint)__shfl_xor((int)aA.z, 32));
    aA.w = pkadd(aA.w, (uint)__shfl_xor((int)aA.w, 32));

    if (q == 0) {
        aA = pk4(aA, g.slf);  // self-loop term h'[v] (prefetched)
        float2 a0 = __half22float2(*(__half2*)&aA.x);
        float2 a1 = __half22float2(*(__half2*)&aA.y);
        float2 a2 = __half22float2(*(__half2*)&aA.z);
        float2 a3 = __half22float2(*(__half2*)&aA.w);
        a0.x = fmaxf(a0.x * dsv + b0.x, 0.f); a0.y = fmaxf(a0.y * dsv + b0.y, 0.f);
        a1.x = fmaxf(a1.x * dsv + b0.z, 0.f); a1.y = fmaxf(a1.y * dsv + b0.w, 0.f);
        a2.x = fmaxf(a2.x * dsv + b1.x, 0.f); a2.y = fmaxf(a2.y * dsv + b1.y, 0.f);
        a3.x = fmaxf(a3.x * dsv + b1.z, 0.f); a3.y = fmaxf(a3.y * dsv + b1.w, 0.f);
        __half2 o0 = __float22half2_rn(a0);
        __half2 o1 = __float22half2_rn(a1);
        __half2 o2 = __float22half2_rn(a2);
        __half2 o3 = __float22half2_rn(a3);
        ((uint4*)out)[v * 16 + l] =
            make_uint4(*(uint*)&o0, *(uint*)&o1, *(uint*)&o2, *(uint*)&o3);
    }
}

__global__ __launch_bounds__(256) void k_agg(const int2* __restrict__ scnt,
                                             const int* __restrict__ esrc,
                                             const ushort* __restrict__ h,
                                             const float* __restrict__ dis,
                                             const float* __restrict__ bias,
                                             ushort* __restrict__ out) {
    const int w = threadIdx.x >> 6;
    const int vb = blockIdx.x * 16 + w * 4;  // 4 nodes per wave; grid exact (100000 = 6250*16)
    const int lane = threadIdx.x & 63, q = lane >> 4, l = lane & 15;
    const uint4* h16 = (const uint4*)h;

    // one-RT preload of all per-node meta + wave constants
    int2 m0 = scnt[vb], m1 = scnt[vb + 1], m2 = scnt[vb + 2], m3 = scnt[vb + 3];
    float d0 = dis[vb], d1 = dis[vb + 1], d2 = dis[vb + 2], d3 = dis[vb + 3];
    float4 b0 = ((const float4*)bias)[2 * l];
    float4 b1 = ((const float4*)bias)[2 * l + 1];

    Ictx c0 = idx_stage(esrc, m0.x, m0.y, q);
    Gt g0 = gather_stage(c0, vb, l, h16);
    Ictx c1 = idx_stage(esrc, m1.x, m1.y, q);
    Gt g1 = gather_stage(c1, vb + 1, l, h16);
    Ictx c2 = idx_stage(esrc, m2.x, m2.y, q);
    acc_finish(g0, c0, vb, q, l, esrc, m0.x, h16, d0, b0, b1, out);
    Gt g2 = gather_stage(c2, vb + 2, l, h16);
    Ictx c3 = idx_stage(esrc, m3.x, m3.y, q);
    acc_finish(g1, c1, vb + 1, q, l, esrc, m1.x, h16, d1, b0, b1, out);
    Gt g3 = gather_stage(c3, vb + 3, l, h16);
    acc_finish(g2, c2, vb + 2, q, l, esrc, m2.x, h16, d2, b0, b1, out);
    acc_finish(g3, c3, vb + 3, q, l, esrc, m3.x, h16, d3, b0, b1, out);
}

// ---------------- final MFMA: out_f32[N][64] = (x1+x2)@Wo + bo ----------------
// 128 rows/block, 512 threads; f32 epilogue LDS-bounce (padded [128][68] f32)
// -> 4 coalesced uint4 stores per thread instead of 16 scattered 4B stores.

__global__ __launch_bounds__(512) void k_final_mfma(const ushort* __restrict__ x1,
                                                    const ushort* __restrict__ x2,
                                                    const ushort* __restrict__ Ws,
                                                    const float* __restrict__ bo,
                                                    float* __restrict__ out) {
    __shared__ ushort sB[64 * 128];   // 16 KB
    __shared__ float sF[128 * 68];    // 34.8 KB; low 32 KB aliased for f16 A staging
    ushort* sA = (ushort*)sF;
    const int tid = threadIdx.x;
    const int row0 = blockIdx.x * 128;

    for (int i = tid; i < 1024; i += 512)
        ((float4*)sB)[i] = ((const float4*)Ws)[i];

    for (int i = tid; i < 4096; i += 512) {
        int m = i >> 5, u = i & 31, k4 = u << 2;
        int r = row0 + m;
        uint2 pk = make_uint2(0, 0);
        if (r < N_NODES) {
            uint2 ua = ((const uint2*)x1)[r * 32 + u];
            uint2 ub = ((const uint2*)x2)[r * 32 + u];
            __half2 s0 = __hadd2(*(__half2*)&ua.x, *(__half2*)&ub.x);
            __half2 s1 = __hadd2(*(__half2*)&ua.y, *(__half2*)&ub.y);
            pk = make_uint2(*(uint*)&s0, *(uint*)&s1);
        }
        *(uint2*)&sA[swz(m, k4)] = pk;
    }
    __syncthreads();

    const int lane = tid & 63, wv = tid >> 6;        // wv 0..7 -> rows wv*16..wv*16+15
    const int mrow = lane & 15, quad = lane >> 4;
    f32x4 acc[4] = {};
#pragma unroll
    for (int kc = 0; kc < 4; ++kc) {
        int g = kc * 4 + quad;
        half8 a = *(const half8*)&sA[(wv * 16 + mrow) * 128 + ((g ^ mrow) << 3)];
#pragma unroll
        for (int nt = 0; nt < 4; ++nt) {
            half8 b = *(const half8*)&sB[(nt * 16 + mrow) * 128 + ((g ^ mrow) << 3)];
            acc[nt] = __builtin_amdgcn_mfma_f32_16x16x32_f16(a, b, acc[nt], 0, 0, 0);
        }
    }

    const int rbase4 = wv * 16 + quad * 4;
    __syncthreads();  // all waves done reading sA/sB
#pragma unroll
    for (int nt = 0; nt < 4; ++nt) {
        float bb = bo[nt * 16 + mrow];
#pragma unroll
        for (int rg = 0; rg < 4; ++rg)
            sF[(rbase4 + rg) * 68 + nt * 16 + mrow] = acc[nt][rg] + bb;
    }
    __syncthreads();

    // coalesced write-out: 2048 uint4 chunks (128 rows x 16 chunks of 4 f32)
#pragma unroll
    for (int k = 0; k < 4; ++k) {
        int idx = tid + k * 512;
        int m = idx >> 4, c16 = idx & 15;
        int r = row0 + m;
        if (r < N_NODES) {
            uint4 vv = *(const uint4*)&sF[m * 68 + c16 * 4];
            ((uint4*)out)[(size_t)r * 16 + c16] = vv;
        }
    }
}

// ---------------- launch ----------------

extern "C" void kernel_launch(void* const* d_in, const int* in_sizes, int n_in,
                              void* d_out, int out_size, void* d_ws, size_t ws_size,
                              hipStream_t stream) {
    const float* x  = (const float*)d_in[0];
    const int*   ei = (const int*)d_in[1];
    const int*   src = ei;
    const int*   dst = ei + N_EDGES;
    const float* W1 = (const float*)d_in[2];
    const float* b1 = (const float*)d_in[3];
    const float* W2 = (const float*)d_in[4];
    const float* b2 = (const float*)d_in[5];
    const float* Wo = (const float*)d_in[6];
    const float* bo = (const float*)d_in[7];
    float* out = (float*)d_out;

    char* ws = (char*)d_ws;
    int*    bfill  = (int*)ws;            ws += 2048;
    int*    bbase  = (int*)ws;            ws += 2048;
    int2*   scnt   = (int2*)ws;           ws += 800000;                    // packed (start,cnt)
    float*  dis    = (float*)ws;          ws += 400000;
    int*    bin    = (int*)ws;            ws += (size_t)NBUCKET * CAP * 4; // 12.8 MB
    int*    esrc   = (int*)ws;            ws += (size_t)N_EDGES * 4;
    ushort* W1s    = (ushort*)ws;         ws += 32768;
    ushort* W2s    = (ushort*)ws;         ws += 32768;
    ushort* WoTs   = (ushort*)ws;         ws += 16384;
    ushort* h      = (ushort*)ws;         ws += (size_t)(N_NODES + 1) * CH * 2;  // +1 zero row
    ushort* x1     = (ushort*)ws;         ws += (size_t)N_NODES * CH * 2;
    ushort* x2     = (ushort*)ws;

    const int gG = (N_NODES + 127) / 128;  // 782 (128 rows/block, 512 threads)
    const int gA = N_NODES / 16;           // 6250 (4 waves x 4 nodes per block)

    // CSR build (LDS-staged counting sort) + weight prep (+ zero row in scan_prep)
    hipMemsetAsync(bfill, 0, 2048, stream);
    k_bin<<<(N_EDGES + BIN_CHUNK - 1) / BIN_CHUNK, 512, 0, stream>>>(src, dst, bfill, bin);
    k_scan_prep<<<82, 512, 0, stream>>>(bfill, bbase, W1, W2, Wo, W1s, W2s, WoTs, h);
    k_build<<<NBUCKET, 256, 0, stream>>>(bfill, bbase, bin, esrc, scnt, dis);

    // layer 1
    k_gemm_mfma<float><<<gG, 512, 0, stream>>>(x, W1s, dis, h);
    k_agg<<<gA, 256, 0, stream>>>(scnt, esrc, h, dis, b1, x1);

    // layer 2
    k_gemm_mfma<ushort><<<gG, 512, 0, stream>>>(x1, W2s, dis, h);
    k_agg<<<gA, 256, 0, stream>>>(scnt, esrc, h, dis, b2, x2);

    // output projection
    k_final_mfma<<<gG, 512, 0, stream>>>(x1, x2, WoTs, bo, out);
}